// Round 12
// baseline (796.898 us; speedup 1.0000x reference)
//
#include <hip/hip_runtime.h>

#define DEVI __device__ __forceinline__

typedef __attribute__((ext_vector_type(4))) float f32x4;
typedef __attribute__((ext_vector_type(8))) __bf16 bf16x8;

static constexpr float EPS = 1.1920929e-07f;
// SCALE(1/sqrt(128)) * log2(e): folded into Q so QK^T scores are log2-domain
static constexpr float SC2L = 0.12751551960234575f;

DEVI float bf2f(unsigned short u){ return __uint_as_float(((unsigned)u)<<16); }
DEVI unsigned short f2bfu(float f){
  unsigned u = __float_as_uint(f);
  u += 0x7fffu + ((u>>16)&1u);
  return (unsigned short)(u>>16);
}
DEVI unsigned pack2(float a, float b){ return (unsigned)f2bfu(a) | ((unsigned)f2bfu(b)<<16); }
DEVI float exp2a(float x){ float r; asm("v_exp_f32 %0, %1" : "=v"(r) : "v"(x)); return r; }
DEVI unsigned cvtpk(float lo, float hi){
  unsigned r; asm("v_cvt_pk_bf16_f32 %0, %1, %2" : "=v"(r) : "v"(lo), "v"(hi)); return r;
}

DEVI void gload16(const void* g, const void* l){
  __builtin_amdgcn_global_load_lds((const __attribute__((address_space(1))) void*)g,
                                   (__attribute__((address_space(3))) void*)l, 16, 0, 0);
}

// ---------------- mask normalization: detect bool-as-bytes vs bool-as-int32 ----------------
__global__ void k_masknorm(const unsigned* __restrict__ vin, const unsigned* __restrict__ cin,
                           unsigned char* __restrict__ vout, unsigned char* __restrict__ cout){
  __shared__ int smode;
  const int t = threadIdx.x;
  if (t==0) smode = 0;
  __syncthreads();
  unsigned loc = 0;
  for (int i=t; i<1024; i+=256) loc |= (vin[i] > 1u);
  if (loc) smode = 1;              // benign race: all writers store 1
  __syncthreads();
  if (smode){                      // byte layout: plain copy (4096 B each)
    for (int i=t; i<1024; i+=256){
      ((unsigned*)vout)[i] = vin[i];
      ((unsigned*)cout)[i] = cin[i];
    }
  } else {                         // int32 layout: compress to bytes
    const int* vi = (const int*)vin; const int* ci = (const int*)cin;
    for (int i=t; i<4096; i+=256){
      vout[i] = (unsigned char)(vi[i] != 0);
      cout[i] = (unsigned char)(ci[i] != 0);
    }
  }
}

// ---------------- converters ----------------
__global__ void k_conv(const float* __restrict__ s, unsigned short* __restrict__ d, int n4){
  int i = blockIdx.x*256 + threadIdx.x;
  if (i >= n4) return;
  float4 v = ((const float4*)s)[i];
  uint2 u; u.x = pack2(v.x, v.y); u.y = pack2(v.z, v.w);
  ((uint2*)d)[i] = u;
}
// w1: [R][C] -> [Rp][C], pad rows with zero
__global__ void k_convpad_rows(const float* __restrict__ s, unsigned short* __restrict__ d,
                               int R, int C, int Rp){
  int i = blockIdx.x*256 + threadIdx.x;
  int total = (Rp*C)>>2;
  if (i >= total) return;
  uint2 u; u.x = 0u; u.y = 0u;
  if (i*4 < R*C){ float4 v = ((const float4*)s)[i]; u.x = pack2(v.x,v.y); u.y = pack2(v.z,v.w); }
  ((uint2*)d)[i] = u;
}
// w2: [N][K] -> [N][Kp], pad inner (K) with zero
__global__ void k_convpad_cols(const float* __restrict__ s, unsigned short* __restrict__ d,
                               int N, int K, int Kp){
  int i = blockIdx.x*256 + threadIdx.x;
  int total = (N*Kp)>>2;
  if (i >= total) return;
  int i4 = i*4; int n = i4/Kp; int k = i4 - n*Kp;
  uint2 u; u.x = 0u; u.y = 0u;
  if (k < K){ float4 v = *(const float4*)(s + (size_t)n*K + k); u.x = pack2(v.x,v.y); u.y = pack2(v.z,v.w); }
  ((uint2*)d)[i] = u;
}

// ---------------- rmsnorm over rows of 2048, fp32 in -> bf16 out ----------------
__global__ void k_rms(const float* __restrict__ X, const float* __restrict__ W,
                      unsigned short* __restrict__ Y){
  const int row = blockIdx.x, tid = threadIdx.x;
  const float* x = X + (size_t)row*2048;
  float4 v0 = ((const float4*)x)[tid*2];
  float4 v1 = ((const float4*)x)[tid*2+1];
  float ss = v0.x*v0.x+v0.y*v0.y+v0.z*v0.z+v0.w*v0.w
           + v1.x*v1.x+v1.y*v1.y+v1.z*v1.z+v1.w*v1.w;
  #pragma unroll
  for (int o=32;o;o>>=1) ss += __shfl_xor(ss, o);
  __shared__ float red[4];
  if ((tid&63)==0) red[tid>>6] = ss;
  __syncthreads();
  float tot = red[0]+red[1]+red[2]+red[3];
  float rs = rsqrtf(tot*(1.0f/2048.0f) + EPS);
  float4 w0 = ((const float4*)W)[tid*2];
  float4 w1 = ((const float4*)W)[tid*2+1];
  uint4 u;
  u.x = pack2(v0.x*rs*w0.x, v0.y*rs*w0.y);
  u.y = pack2(v0.z*rs*w0.z, v0.w*rs*w0.w);
  u.z = pack2(v1.x*rs*w1.x, v1.y*rs*w1.y);
  u.w = pack2(v1.z*rs*w1.z, v1.w*rs*w1.w);
  *(uint4*)(Y + (size_t)row*2048 + tid*8) = u;
}

// ---------------- legacy GEMM (m97 structure), used for wkv only ----------------
template<int EPI>
__global__ void k_gemm(const unsigned short* __restrict__ A, const unsigned short* __restrict__ Bw,
                       void* Cout, const float* resid, int M, int N, int K){
  __shared__ __align__(16) unsigned short sm[16384];
  const int tid = threadIdx.x;
  const int w = tid>>6, l = tid&63, g = l>>4, q = l&15;
  const int bm = blockIdx.y<<7, bn = blockIdx.x<<7;
  const int wr = (w>>1)<<6, wc = (w&1)<<6;
  f32x4 acc[4][4];
  #pragma unroll
  for (int a=0;a<4;++a)
    #pragma unroll
    for (int b2=0;b2<4;++b2) acc[a][b2] = f32x4{0.f,0.f,0.f,0.f};

  const unsigned short* Ag = A + (size_t)bm*K;
  const unsigned short* Bg = Bw + (size_t)bn*K;
  const int nk = K>>5;
  int cur = 0;

  auto STAGE = [&](int buf, int kt){
    #pragma unroll
    for (int i=0;i<2;++i){
      int L = (i*256+tid)*16;
      int r = L>>6; int ce = (L&63)>>1;
      int lofs = __builtin_amdgcn_readfirstlane(buf*8192 + i*4096 + (tid>>6)*1024);
      gload16(Ag + (size_t)r*K + (kt<<5) + ce, (const char*)sm + lofs);
    }
    #pragma unroll
    for (int i=0;i<2;++i){
      int L = (i*256+tid)*16;
      int r = L>>6; int ce = (L&63)>>1;
      int lofs = __builtin_amdgcn_readfirstlane(16384 + buf*8192 + i*4096 + (tid>>6)*1024);
      gload16(Bg + (size_t)r*K + (kt<<5) + ce, (const char*)sm + lofs);
    }
  };

  STAGE(0, 0);
  __syncthreads();
  for (int kt=0; kt<nk; ++kt){
    if (kt+1 < nk) STAGE(cur^1, kt+1);
    const unsigned short* Ab = sm + cur*4096;
    const unsigned short* Bb = sm + 8192 + cur*4096;
    bf16x8 af[4], bfr[4];
    #pragma unroll
    for (int mi=0;mi<4;++mi) af[mi] = *(const bf16x8*)(Ab + (wr + mi*16 + q)*32 + g*8);
    #pragma unroll
    for (int ni=0;ni<4;++ni) bfr[ni] = *(const bf16x8*)(Bb + (wc + ni*16 + q)*32 + g*8);
    #pragma unroll
    for (int mi=0;mi<4;++mi)
      #pragma unroll
      for (int ni=0;ni<4;++ni)
        acc[mi][ni] = __builtin_amdgcn_mfma_f32_16x16x32_bf16(af[mi], bfr[ni], acc[mi][ni], 0,0,0);
    __syncthreads();
    cur ^= 1;
  }
  #pragma unroll
  for (int mi=0;mi<4;++mi)
    #pragma unroll
    for (int ni=0;ni<4;++ni)
      #pragma unroll
      for (int r=0;r<4;++r){
        int row = bm + wr + mi*16 + g*4 + r;
        int col = bn + wc + ni*16 + q;
        size_t idx = (size_t)row*N + col;
        float v = acc[mi][ni][r];
        if (EPI==0) ((unsigned short*)Cout)[idx] = f2bfu(v);
        else if (EPI==1){ float sg = v/(1.0f+__expf(-v)); ((unsigned short*)Cout)[idx] = f2bfu(sg); }
        else ((float*)Cout)[idx] = resid[idx] + v;
      }
}

// ---------------- 128x256 GEMM, ROUND 12: BK=32, ring-3 (72 KB) -> 2 blocks/CU ----------------
// Occupancy doubled (16 waves/CU): cross-block implicit overlap fills vmcnt/barrier bubbles
// (the m97/m114 mechanism). Counted vmcnt: 3 loads/thread/K-tile, gate vmcnt(3), never 0
// mid-loop. Rows are 64 B = 4 chunks; swizzle c = g ^ ((row>>1)&3) -> 2-way aliasing (free),
// staged via pre-swizzled global source (both-sides involution).
// EPI: 0 = store bf16, 1 = silu->bf16, 2 = fp32 resid add -> fp32 out
template<int EPI>
__global__ __launch_bounds__(512,4)
void k_gemm2(const unsigned short* __restrict__ A, const unsigned short* __restrict__ Bw,
             void* Cout, const float* resid, int M, int N, int K){
  __shared__ __align__(16) char sm[73728];        // 3 x (A 128x32 [8K] | B 256x32 [16K])
  const int tid = threadIdx.x;
  const int wid = tid>>6, l = tid&63, g = l>>4, q = l&15;
  const int wm = wid>>2, wn = wid&3;
  // column-major XCD chunking (neutral; kept from round 11; grids always nwg%8==0)
  const int gy = gridDim.y;
  const int orig = blockIdx.y*gridDim.x + blockIdx.x;
  const int qq = (gridDim.x*gy)>>3;
  const int nid = (orig&7)*qq + (orig>>3);
  const int bm = (nid % gy) << 7;
  const int bn = (nid / gy) << 8;
  f32x4 acc[4][4];
  #pragma unroll
  for (int a=0;a<4;++a)
    #pragma unroll
    for (int b2=0;b2<4;++b2) acc[a][b2] = f32x4{0.f,0.f,0.f,0.f};

  const unsigned short* Ag = A + (size_t)bm*K;
  const unsigned short* Bg = Bw + (size_t)bn*K;
  const int nk = K>>5;

  // A tile 8192 B: 1 load/thread. row lr = tid>>2, chunk c8 = tid&3, src chunk pre-swizzled.
  auto STAGE_A = [&](int buf, int kt){
    int lr = tid>>2, c8 = tid&3;
    int cg = c8 ^ ((lr>>1)&3);
    int lofs = __builtin_amdgcn_readfirstlane(buf*24576 + wid*1024);
    gload16(Ag + (size_t)lr*K + (kt<<5) + cg*8, sm + lofs);
  };
  // B tile 16384 B: 2 loads/thread.
  auto STAGE_B = [&](int buf, int kt){
    #pragma unroll
    for (int j=0;j<2;++j){
      int rn = (j*512+tid)>>2, c8 = tid&3;
      int cg = c8 ^ ((rn>>1)&3);
      int lofs = __builtin_amdgcn_readfirstlane(buf*24576 + 8192 + j*8192 + wid*1024);
      gload16(Bg + (size_t)rn*K + (kt<<5) + cg*8, sm + lofs);
    }
  };

  // prologue: prefetch K-tiles 0 and 1 (3 loads/thread each); nk >= 2 for all shapes here
  STAGE_A(0,0); STAGE_B(0,0);
  STAGE_A(1,1); STAGE_B(1,1);

  int buf = 0;
  for (int kt=0; kt<nk; ++kt){
    int p2 = buf+2; if (p2>2) p2-=3;
    // gate: tile kt's 3 loads landed; tile kt+1's 3 stay in flight
    if (kt+1 < nk) asm volatile("s_waitcnt vmcnt(3)" ::: "memory");
    else           asm volatile("s_waitcnt vmcnt(0)" ::: "memory");
    asm volatile("s_waitcnt lgkmcnt(0)" ::: "memory");   // my frag reads of buf(kt-1) retired
    __builtin_amdgcn_s_barrier();
    asm volatile("" ::: "memory");
    if (kt+2 < nk){ STAGE_A(p2, kt+2); STAGE_B(p2, kt+2); }  // refill buf(kt-1)

    const char* Ab = sm + buf*24576;
    const char* Bb = Ab + 8192;
    bf16x8 af[4], bfr[4];
    #pragma unroll
    for (int mi=0;mi<4;++mi){
      int lr = wm*64 + mi*16 + q;
      af[mi] = *(const bf16x8*)(Ab + lr*64 + ((g ^ ((lr>>1)&3))<<4));
    }
    #pragma unroll
    for (int ni=0;ni<4;++ni){
      int rn = wn*64 + ni*16 + q;
      bfr[ni] = *(const bf16x8*)(Bb + rn*64 + ((g ^ ((rn>>1)&3))<<4));
    }
    asm volatile("s_waitcnt lgkmcnt(0)" ::: "memory");
    __builtin_amdgcn_sched_barrier(0);                   // rule #18: pin MFMA below the wait
    __builtin_amdgcn_s_setprio(1);
    #pragma unroll
    for (int mi=0;mi<4;++mi)
      #pragma unroll
      for (int ni=0;ni<4;++ni)
        acc[mi][ni] = __builtin_amdgcn_mfma_f32_16x16x32_bf16(af[mi], bfr[ni], acc[mi][ni], 0,0,0);
    __builtin_amdgcn_s_setprio(0);
    buf = (buf==2) ? 0 : buf+1;
  }

  #pragma unroll
  for (int mi=0;mi<4;++mi)
    #pragma unroll
    for (int ni=0;ni<4;++ni)
      #pragma unroll
      for (int r=0;r<4;++r){
        int row = bm + wm*64 + mi*16 + g*4 + r;
        int col = bn + wn*64 + ni*16 + q;
        size_t idx = (size_t)row*N + col;
        float v = acc[mi][ni][r];
        if (EPI==0) ((unsigned short*)Cout)[idx] = f2bfu(v);
        else if (EPI==1){ float sg = v/(1.0f+__expf(-v)); ((unsigned short*)Cout)[idx] = f2bfu(sg); }
        else ((float*)Cout)[idx] = resid[idx] + v;
      }
}

// ---------------- self QKV postprocess: QK-norm + RoPE; V -> transposed layout ----------------
__global__ void k_self_pp(const unsigned short* __restrict__ qkv, const float* __restrict__ fc,
                          const float* __restrict__ fs, const float* __restrict__ qn,
                          const float* __restrict__ kn,
                          unsigned short* __restrict__ Qb, unsigned short* __restrict__ Kb,
                          unsigned short* __restrict__ Vt){
  const int row = blockIdx.x;           // b*2048 + s
  const int b = row>>11, s = row&2047;
  const int w = threadIdx.x>>6, l = threadIdx.x&63;
  const int d0 = 2*l, d1 = d0+1;
  const float c0 = fc[s*128+d0], c1 = fc[s*128+d1];
  const float s0 = fs[s*128+d0], s1 = fs[s*128+d1];
  #pragma unroll
  for (int it=0; it<6; ++it){
    const int hh = it*4 + w;
    const unsigned short* src = qkv + (size_t)row*3072 + hh*128;
    if (hh >= 20){
      const int hv = hh - 20;
      size_t base = ((size_t)(b*4 + hv))*128*2048;
      Vt[base + (size_t)d0*2048 + s] = src[d0];
      Vt[base + (size_t)d1*2048 + s] = src[d1];
    } else {
      float x0 = bf2f(src[d0]), x1 = bf2f(src[d1]);
      float ss = x0*x0 + x1*x1;
      #pragma unroll
      for (int o=32;o;o>>=1) ss += __shfl_xor(ss, o);
      float rs = rsqrtf(ss*(1.0f/128.0f) + EPS);
      if (hh < 16){
        float y0 = x0*rs*qn[d0], y1 = x1*rs*qn[d1];
        *(unsigned*)(Qb + (((size_t)(b*16 + hh)*2048 + s)*128) + d0)
          = pack2((y0*c0 - y1*s0)*SC2L, (y1*c1 + y0*s1)*SC2L);
      } else {
        float y0 = x0*rs*kn[d0], y1 = x1*rs*kn[d1];
        *(unsigned*)(Kb + (((size_t)(b*4 + (hh-16))*2048 + s)*128) + d0)
          = pack2(y0*c0 - y1*s0, y1*c1 + y0*s1);
      }
    }
  }
}

// ---------------- cross Q postprocess: RoPE FIRST then rmsnorm (Q scaled by SC2L) ----------------
__global__ void k_crossq_pp(const unsigned short* __restrict__ qc, const float* __restrict__ fc,
                            const float* __restrict__ fs, const float* __restrict__ qn,
                            unsigned short* __restrict__ Qb){
  const int row = blockIdx.x;
  const int b = row>>11, s = row&2047;
  const int w = threadIdx.x>>6, l = threadIdx.x&63;
  const int d0 = 2*l, d1 = d0+1;
  const float c0 = fc[s*128+d0], c1 = fc[s*128+d1];
  const float s0 = fs[s*128+d0], s1 = fs[s*128+d1];
  #pragma unroll
  for (int it=0; it<4; ++it){
    const int hh = it*4 + w;
    const unsigned short* src = qc + (size_t)row*2048 + hh*128;
    float x0 = bf2f(src[d0]), x1 = bf2f(src[d1]);
    float y0 = x0*c0 - x1*s0;
    float y1 = x1*c1 + x0*s1;
    float ss = y0*y0 + y1*y1;
    #pragma unroll
    for (int o=32;o;o>>=1) ss += __shfl_xor(ss, o);
    float rs = rsqrtf(ss*(1.0f/128.0f) + EPS);
    *(unsigned*)(Qb + (((size_t)(b*16 + hh)*2048 + s)*128) + d0)
      = pack2(y0*rs*qn[d0]*SC2L, y1*rs*qn[d1]*SC2L);
  }
}

// ---------------- cross KV postprocess: K rmsnorm (no rope); V transposed copy ----------------
__global__ void k_crosskv_pp(const unsigned short* __restrict__ kvc, const float* __restrict__ kn,
                             unsigned short* __restrict__ Kb, unsigned short* __restrict__ Vt){
  const int row = blockIdx.x;           // b*2048 + sctx
  const int b = row>>11, s = row&2047;
  const int w = threadIdx.x>>6, l = threadIdx.x&63;
  const int d0 = 2*l, d1 = d0+1;
  #pragma unroll
  for (int it=0; it<2; ++it){
    const int hh = it*4 + w;
    const unsigned short* src = kvc + (size_t)row*1024 + hh*128;
    if (hh < 4){
      float x0 = bf2f(src[d0]), x1 = bf2f(src[d1]);
      float ss = x0*x0 + x1*x1;
      #pragma unroll
      for (int o=32;o;o>>=1) ss += __shfl_xor(ss, o);
      float rs = rsqrtf(ss*(1.0f/128.0f) + EPS);
      *(unsigned*)(Kb + (((size_t)(b*4 + hh)*2048 + s)*128) + d0)
        = pack2(x0*rs*kn[d0], x1*rs*kn[d1]);
    } else {
      const int hv = hh-4;
      size_t base = ((size_t)(b*4 + hv))*128*2048;
      Vt[base + (size_t)d0*2048 + s] = src[d0];
      Vt[base + (size_t)d1*2048 + s] = src[d1];
    }
  }
}

// ---------------- flash attention, GQA head-fused (round 9, unchanged) ----------------
template<bool QMASK>
__global__ __launch_bounds__(1024,1)
void k_attn(const unsigned short* __restrict__ Qg, const unsigned short* __restrict__ Kg,
            const unsigned short* __restrict__ Vtg,
            const unsigned char* __restrict__ qm, const unsigned char* __restrict__ km,
            unsigned short* __restrict__ Og, int H, int HKV){
  constexpr int SK = 2048, SQ = 2048, NT = SK/64;
  __shared__ __align__(16) char smem[106496];
  const int qt = blockIdx.x, hk = blockIdx.y, b = blockIdx.z;
  const int REP = H/HKV;
  const int tid = threadIdx.x, w = tid>>6, l = tid&63, g = l>>4, q = l&15;
  const int hq = w>>2, wsub = w&3;

  if (tid < 256){ // build f32 mask-bias table (0 visible, -3e38 masked)
    const unsigned long long mv = ((const unsigned long long*)(km + (size_t)b*SK))[tid];
    float* bl = (float*)(smem + 98304);
    #pragma unroll
    for (int j=0;j<8;++j)
      bl[tid*8+j] = ((mv>>(8*j)) & 0xffull) ? 0.0f : -3.0e38f;
  }

  const int h = hk*REP + hq;
  const size_t qrow = (size_t)(b*H + h)*SQ + qt*64 + wsub*16 + q;
  bf16x8 qf[4];
  #pragma unroll
  for (int ks=0;ks<4;++ks) qf[ks] = *(const bf16x8*)(Qg + qrow*128 + ks*32 + g*8);

  f32x4 oacc[8];
  #pragma unroll
  for (int i=0;i<8;++i) oacc[i] = f32x4{0.f,0.f,0.f,0.f};
  float m_run = -1.0e30f, l_run = 0.f;

  const unsigned short* Kt0 = Kg + (size_t)(b*HKV + hk)*SK*128;
  const unsigned short* Vt0 = Vtg + (size_t)(b*HKV + hk)*128*SK;
  const float* biasf = (const float*)(smem + 98304);
  char* Pl = smem + 65536 + w*2048;

  auto STAGE_T = [&](int t, int p){
    { // K: thread tid covers row r=tid>>4, chunk c16=tid&15
      int r = tid>>4, c16 = tid&15;
      int c = (c16 & 8) | ((c16 & 7) ^ (r & 7));
      int lofs = __builtin_amdgcn_readfirstlane(p*16384 + w*1024);
      gload16(Kt0 + (size_t)(t*64 + r)*128 + c*8, smem + lofs);
    }
    { // Vt: thread tid covers d=tid>>3, chunk c8=tid&7
      int d = tid>>3, c8 = tid&7;
      int c = c8 ^ (d & 7);
      int lofs = __builtin_amdgcn_readfirstlane(32768 + p*16384 + w*1024);
      gload16(Vt0 + (size_t)d*SK + t*64 + c*8, smem + lofs);
    }
  };

  STAGE_T(0, 0);

  for (int t=0; t<NT; ++t){
    const int p = t&1;
    asm volatile("s_waitcnt lgkmcnt(0)" ::: "memory");
    __builtin_amdgcn_s_barrier();
    asm volatile("" ::: "memory");
    if (t+1 < NT){
      STAGE_T(t+1, p^1);
      asm volatile("s_waitcnt vmcnt(2)" ::: "memory");  // tile t landed; t+1's 2 loads in flight
    } else {
      asm volatile("s_waitcnt vmcnt(0)" ::: "memory");
    }
    __builtin_amdgcn_s_barrier();
    asm volatile("" ::: "memory");

    const char* Kb_ = smem + p*16384;
    const char* Vb_ = smem + 32768 + p*16384;

    // S^T = K . Q (log2 domain)
    f32x4 sacc[4];
    #pragma unroll
    for (int i=0;i<4;++i) sacc[i] = f32x4{0.f,0.f,0.f,0.f};
    __builtin_amdgcn_s_setprio(1);
    #pragma unroll
    for (int ks=0;ks<4;++ks){
      #pragma unroll
      for (int mi=0;mi<4;++mi){
        int kcol = mi*16 + q;
        int c = 4*ks + g;
        int c16 = (c & 8) | ((c & 7) ^ (kcol & 7));
        bf16x8 ak = *(const bf16x8*)(Kb_ + kcol*256 + c16*16);
        sacc[mi] = __builtin_amdgcn_mfma_f32_16x16x32_bf16(ak, qf[ks], sacc[mi], 0,0,0);
      }
    }
    __builtin_amdgcn_s_setprio(0);

    // online softmax (log2) + mask bias + defer-max
    float sv[4][4];
    float mloc = -3.0e38f;
    #pragma unroll
    for (int mi=0;mi<4;++mi){
      f32x4 bb = *(const f32x4*)(biasf + t*64 + mi*16 + g*4);
      #pragma unroll
      for (int r=0;r<4;++r){
        float v = sacc[mi][r] + bb[r];
        sv[mi][r] = v;
        mloc = fmaxf(mloc, v);
      }
    }
    mloc = fmaxf(mloc, __shfl_xor(mloc, 16));
    mloc = fmaxf(mloc, __shfl_xor(mloc, 32));
    if (!__all(mloc - m_run <= 8.0f)){
      float mnew = fmaxf(m_run, mloc);
      float alpha = exp2a(m_run - mnew);
      l_run *= alpha;
      #pragma unroll
      for (int i=0;i<8;++i) oacc[i] *= alpha;
      m_run = mnew;
    }
    float rsum = 0.f;
    unsigned pb[4][2];
    #pragma unroll
    for (int mi=0;mi<4;++mi){
      float p0 = exp2a(sv[mi][0] - m_run);
      float p1 = exp2a(sv[mi][1] - m_run);
      float p2 = exp2a(sv[mi][2] - m_run);
      float p3 = exp2a(sv[mi][3] - m_run);
      rsum += (p0+p1)+(p2+p3);
      pb[mi][0] = cvtpk(p0, p1);
      pb[mi][1] = cvtpk(p2, p3);
    }
    rsum += __shfl_xor(rsum, 16);
    rsum += __shfl_xor(rsum, 32);
    l_run += rsum;

    // P -> wave-private LDS (XOR chunk swizzle)
    #pragma unroll
    for (int mi=0;mi<4;++mi){
      int c16 = (2*mi + (g>>1)) ^ (q & 7);
      uint2 uu; uu.x = pb[mi][0]; uu.y = pb[mi][1];
      *(uint2*)(Pl + q*128 + c16*16 + (g&1)*8) = uu;
    }
    asm volatile("" ::: "memory");

    // O^T += Vt . P^T
    __builtin_amdgcn_s_setprio(1);
    #pragma unroll
    for (int ks=0;ks<2;++ks){
      int c16 = (4*ks + g) ^ (q & 7);
      bf16x8 pf = *(const bf16x8*)(Pl + q*128 + c16*16);
      #pragma unroll
      for (int mi=0;mi<8;++mi){
        int d = mi*16 + q;
        bf16x8 vf = *(const bf16x8*)(Vb_ + d*128 + c16*16);
        oacc[mi] = __builtin_amdgcn_mfma_f32_16x16x32_bf16(vf, pf, oacc[mi], 0,0,0);
      }
    }
    __builtin_amdgcn_s_setprio(0);
  }

  float inv = (l_run > 0.f) ? 1.0f/l_run : 0.f;
  if (QMASK){
    if (!qm[(size_t)b*SQ + qt*64 + wsub*16 + q]) inv = 0.f;
  }
  // per-head transpose + store, 4 sequential phases (all 16 waves store each phase)
  float* Ot = (float*)smem;               // [128][65] f32 = 33,280 B
  const int qloc = tid>>4, seg = tid&15;
  #pragma unroll
  for (int ph=0; ph<4; ++ph){
    __syncthreads();
    if (hq == ph){
      #pragma unroll
      for (int mi=0;mi<8;++mi)
        #pragma unroll
        for (int r=0;r<4;++r){
          int d = mi*16 + g*4 + r;
          Ot[d*65 + wsub*16 + q] = oacc[mi][r]*inv;
        }
    }
    __syncthreads();
    int srow = qt*64 + qloc;
    size_t obase = ((size_t)b*SQ + srow)*(size_t)(H*128) + (size_t)(hk*REP + ph)*128 + seg*8;
    float vv[8];
    #pragma unroll
    for (int j=0;j<8;++j) vv[j] = Ot[(seg*8 + j)*65 + qloc];
    uint4 u;
    u.x = pack2(vv[0],vv[1]); u.y = pack2(vv[2],vv[3]);
    u.z = pack2(vv[4],vv[5]); u.w = pack2(vv[6],vv[7]);
    *(uint4*)(Og + obase) = u;
  }
}

// ---------------- launch ----------------
extern "C" void kernel_launch(void* const* d_in, const int* in_sizes, int n_in,
                              void* d_out, int out_size, void* d_ws, size_t ws_size,
                              hipStream_t stream){
  const float* x        = (const float*)d_in[0];
  const float* ctx      = (const float*)d_in[1];
  const float* fc       = (const float*)d_in[2];
  const float* fs       = (const float*)d_in[3];
  const float* wqkv     = (const float*)d_in[4];
  const float* wo_self  = (const float*)d_in[5];
  const float* qn_self  = (const float*)d_in[6];
  const float* kn_self  = (const float*)d_in[7];
  const float* wq       = (const float*)d_in[8];
  const float* wkv      = (const float*)d_in[9];
  const float* wo_cross = (const float*)d_in[10];
  const float* qn_cross = (const float*)d_in[11];
  const float* kn_cross = (const float*)d_in[12];
  const float* w1       = (const float*)d_in[13];
  const float* w2       = (const float*)d_in[14];
  const float* attn_nw  = (const float*)d_in[15];
  const float* cross_nw = (const float*)d_in[16];
  const float* ffn_nw   = (const float*)d_in[17];
  const unsigned* vis_raw   = (const unsigned*)d_in[18];
  const unsigned* cmask_raw = (const unsigned*)d_in[19];
  float* out = (float*)d_out;

  // HID padded 5464 -> 5632 (divisible by 256) for the new GEMM; zero-pad keeps exactness.
  char* ws = (char*)d_ws;
  unsigned short* wslot = (unsigned short*)(ws);               // 23,068,672 B (5632x2048 bf16)
  unsigned short* ctxbf = (unsigned short*)(ws +  23068672);   // 16,777,216
  unsigned short* nbuf  = (unsigned short*)(ws +  39845888);   // 16,777,216
  unsigned short* qkvb  = (unsigned short*)(ws +  56623104);   // 25,165,824
  unsigned short* Qb    = (unsigned short*)(ws +  81788928);   // 16,777,216
  unsigned short* Kb    = (unsigned short*)(ws +  98566144);   //  4,194,304
  unsigned short* Vtb   = (unsigned short*)(ws + 102760448);   //  4,194,304
  unsigned short* aob   = (unsigned short*)(ws + 106954752);   // aliased with midb (aob dead before w1)
  unsigned short* midb  = (unsigned short*)(ws + 106954752);   // 46,137,344 (4096x5632 bf16)
  unsigned char*  visN  = (unsigned char*)(ws + 153092096);    //  4,096
  unsigned char*  cmkN  = (unsigned char*)(ws + 153096192);    //  4,096 -> end 153,100,288
  unsigned short* qcb   = qkvb;                                // cross-q reuses qkv buffer
  unsigned short* kvcb  = qkvb + 8388608;                      // +16,777,216 B

  auto conv = [&](const float* s, unsigned short* dst, size_t n){
    int n4 = (int)(n>>2);
    k_conv<<<(n4+255)/256, 256, 0, stream>>>(s, dst, n4);
  };

  // ---- canonicalize masks (bool-as-bytes vs bool-as-int32) ----
  k_masknorm<<<1,256,0,stream>>>(vis_raw, cmask_raw, visN, cmkN);

  // ---- self attention path ----
  conv(ctx, ctxbf, (size_t)4096*2048);
  k_rms<<<4096,256,0,stream>>>(x, attn_nw, nbuf);
  conv(wqkv, wslot, (size_t)3072*2048);
  k_gemm2<0><<<dim3(12,32),512,0,stream>>>(nbuf, wslot, qkvb, nullptr, 4096,3072,2048);
  k_self_pp<<<4096,256,0,stream>>>(qkvb, fc, fs, qn_self, kn_self, Qb, Kb, Vtb);
  k_attn<true><<<dim3(32,4,2),1024,0,stream>>>(Qb, Kb, Vtb, visN, visN, aob, 16, 4);
  conv(wo_self, wslot, (size_t)2048*2048);
  k_gemm2<2><<<dim3(8,32),512,0,stream>>>(aob, wslot, out, x, 4096,2048,2048);

  // ---- cross attention path ----
  k_rms<<<4096,256,0,stream>>>(out, cross_nw, nbuf);
  conv(wq, wslot, (size_t)2048*2048);
  k_gemm2<0><<<dim3(8,32),512,0,stream>>>(nbuf, wslot, qcb, nullptr, 4096,2048,2048);
  conv(wkv, wslot, (size_t)1024*2048);
  k_gemm<0><<<dim3(8,32),256,0,stream>>>(ctxbf, wslot, kvcb, nullptr, 4096,1024,2048);
  k_crossq_pp<<<4096,256,0,stream>>>(qcb, fc, fs, qn_cross, Qb);
  k_crosskv_pp<<<4096,256,0,stream>>>(kvcb, kn_cross, Kb, Vtb);
  k_attn<false><<<dim3(32,4,2),1024,0,stream>>>(Qb, Kb, Vtb, nullptr, cmkN, aob, 16, 4);
  conv(wo_cross, wslot, (size_t)2048*2048);
  k_gemm2<2><<<dim3(8,32),512,0,stream>>>(aob, wslot, out, out, 4096,2048,2048);

  // ---- FFN (silu MLP), HID padded 5464 -> 5632 ----
  k_rms<<<4096,256,0,stream>>>(out, ffn_nw, nbuf);
  k_convpad_rows<<<(5632*2048/4+255)/256,256,0,stream>>>(w1, wslot, 5464, 2048, 5632);
  k_gemm2<1><<<dim3(22,32),512,0,stream>>>(nbuf, wslot, midb, nullptr, 4096,5632,2048);
  k_convpad_cols<<<(2048*5632/4+255)/256,256,0,stream>>>(w2, wslot, 2048, 5464, 5632);
  k_gemm2<2><<<dim3(8,32),512,0,stream>>>(midb, wslot, out, out, 4096,2048,5632);

  (void)in_sizes; (void)n_in; (void)out_size; (void)ws_size;
}

// Round 13
// 771.524 us; speedup vs baseline: 1.0329x; 1.0329x over previous
//
#include <hip/hip_runtime.h>

#define DEVI __device__ __forceinline__

typedef __attribute__((ext_vector_type(4))) float f32x4;
typedef __attribute__((ext_vector_type(8))) __bf16 bf16x8;

static constexpr float EPS = 1.1920929e-07f;
// SCALE(1/sqrt(128)) * log2(e): folded into Q so QK^T scores are log2-domain
static constexpr float SC2L = 0.12751551960234575f;

DEVI float bf2f(unsigned short u){ return __uint_as_float(((unsigned)u)<<16); }
DEVI unsigned short f2bfu(float f){
  unsigned u = __float_as_uint(f);
  u += 0x7fffu + ((u>>16)&1u);
  return (unsigned short)(u>>16);
}
DEVI unsigned pack2(float a, float b){ return (unsigned)f2bfu(a) | ((unsigned)f2bfu(b)<<16); }
DEVI float exp2a(float x){ float r; asm("v_exp_f32 %0, %1" : "=v"(r) : "v"(x)); return r; }
DEVI unsigned cvtpk(float lo, float hi){
  unsigned r; asm("v_cvt_pk_bf16_f32 %0, %1, %2" : "=v"(r) : "v"(lo), "v"(hi)); return r;
}

DEVI void gload16(const void* g, const void* l){
  __builtin_amdgcn_global_load_lds((const __attribute__((address_space(1))) void*)g,
                                   (__attribute__((address_space(3))) void*)l, 16, 0, 0);
}

// ---------------- mask normalization: detect bool-as-bytes vs bool-as-int32 ----------------
__global__ void k_masknorm(const unsigned* __restrict__ vin, const unsigned* __restrict__ cin,
                           unsigned char* __restrict__ vout, unsigned char* __restrict__ cout){
  __shared__ int smode;
  const int t = threadIdx.x;
  if (t==0) smode = 0;
  __syncthreads();
  unsigned loc = 0;
  for (int i=t; i<1024; i+=256) loc |= (vin[i] > 1u);
  if (loc) smode = 1;              // benign race: all writers store 1
  __syncthreads();
  if (smode){                      // byte layout: plain copy (4096 B each)
    for (int i=t; i<1024; i+=256){
      ((unsigned*)vout)[i] = vin[i];
      ((unsigned*)cout)[i] = cin[i];
    }
  } else {                         // int32 layout: compress to bytes
    const int* vi = (const int*)vin; const int* ci = (const int*)cin;
    for (int i=t; i<4096; i+=256){
      vout[i] = (unsigned char)(vi[i] != 0);
      cout[i] = (unsigned char)(ci[i] != 0);
    }
  }
}

// ---------------- converters ----------------
__global__ void k_conv(const float* __restrict__ s, unsigned short* __restrict__ d, int n4){
  int i = blockIdx.x*256 + threadIdx.x;
  if (i >= n4) return;
  float4 v = ((const float4*)s)[i];
  uint2 u; u.x = pack2(v.x, v.y); u.y = pack2(v.z, v.w);
  ((uint2*)d)[i] = u;
}
// w1: [R][C] -> [Rp][C], pad rows with zero
__global__ void k_convpad_rows(const float* __restrict__ s, unsigned short* __restrict__ d,
                               int R, int C, int Rp){
  int i = blockIdx.x*256 + threadIdx.x;
  int total = (Rp*C)>>2;
  if (i >= total) return;
  uint2 u; u.x = 0u; u.y = 0u;
  if (i*4 < R*C){ float4 v = ((const float4*)s)[i]; u.x = pack2(v.x,v.y); u.y = pack2(v.z,v.w); }
  ((uint2*)d)[i] = u;
}
// w2: [N][K] -> [N][Kp], pad inner (K) with zero
__global__ void k_convpad_cols(const float* __restrict__ s, unsigned short* __restrict__ d,
                               int N, int K, int Kp){
  int i = blockIdx.x*256 + threadIdx.x;
  int total = (N*Kp)>>2;
  if (i >= total) return;
  int i4 = i*4; int n = i4/Kp; int k = i4 - n*Kp;
  uint2 u; u.x = 0u; u.y = 0u;
  if (k < K){ float4 v = *(const float4*)(s + (size_t)n*K + k); u.x = pack2(v.x,v.y); u.y = pack2(v.z,v.w); }
  ((uint2*)d)[i] = u;
}

// ---------------- rmsnorm over rows of 2048, fp32 in -> bf16 out ----------------
__global__ void k_rms(const float* __restrict__ X, const float* __restrict__ W,
                      unsigned short* __restrict__ Y){
  const int row = blockIdx.x, tid = threadIdx.x;
  const float* x = X + (size_t)row*2048;
  float4 v0 = ((const float4*)x)[tid*2];
  float4 v1 = ((const float4*)x)[tid*2+1];
  float ss = v0.x*v0.x+v0.y*v0.y+v0.z*v0.z+v0.w*v0.w
           + v1.x*v1.x+v1.y*v1.y+v1.z*v1.z+v1.w*v1.w;
  #pragma unroll
  for (int o=32;o;o>>=1) ss += __shfl_xor(ss, o);
  __shared__ float red[4];
  if ((tid&63)==0) red[tid>>6] = ss;
  __syncthreads();
  float tot = red[0]+red[1]+red[2]+red[3];
  float rs = rsqrtf(tot*(1.0f/2048.0f) + EPS);
  float4 w0 = ((const float4*)W)[tid*2];
  float4 w1 = ((const float4*)W)[tid*2+1];
  uint4 u;
  u.x = pack2(v0.x*rs*w0.x, v0.y*rs*w0.y);
  u.y = pack2(v0.z*rs*w0.z, v0.w*rs*w0.w);
  u.z = pack2(v1.x*rs*w1.x, v1.y*rs*w1.y);
  u.w = pack2(v1.z*rs*w1.z, v1.w*rs*w1.w);
  *(uint4*)(Y + (size_t)row*2048 + tid*8) = u;
}

// ---------------- legacy GEMM (m97 structure), used for wkv only ----------------
template<int EPI>
__global__ void k_gemm(const unsigned short* __restrict__ A, const unsigned short* __restrict__ Bw,
                       void* Cout, const float* resid, int M, int N, int K){
  __shared__ __align__(16) unsigned short sm[16384];
  const int tid = threadIdx.x;
  const int w = tid>>6, l = tid&63, g = l>>4, q = l&15;
  const int bm = blockIdx.y<<7, bn = blockIdx.x<<7;
  const int wr = (w>>1)<<6, wc = (w&1)<<6;
  f32x4 acc[4][4];
  #pragma unroll
  for (int a=0;a<4;++a)
    #pragma unroll
    for (int b2=0;b2<4;++b2) acc[a][b2] = f32x4{0.f,0.f,0.f,0.f};

  const unsigned short* Ag = A + (size_t)bm*K;
  const unsigned short* Bg = Bw + (size_t)bn*K;
  const int nk = K>>5;
  int cur = 0;

  auto STAGE = [&](int buf, int kt){
    #pragma unroll
    for (int i=0;i<2;++i){
      int L = (i*256+tid)*16;
      int r = L>>6; int ce = (L&63)>>1;
      int lofs = __builtin_amdgcn_readfirstlane(buf*8192 + i*4096 + (tid>>6)*1024);
      gload16(Ag + (size_t)r*K + (kt<<5) + ce, (const char*)sm + lofs);
    }
    #pragma unroll
    for (int i=0;i<2;++i){
      int L = (i*256+tid)*16;
      int r = L>>6; int ce = (L&63)>>1;
      int lofs = __builtin_amdgcn_readfirstlane(16384 + buf*8192 + i*4096 + (tid>>6)*1024);
      gload16(Bg + (size_t)r*K + (kt<<5) + ce, (const char*)sm + lofs);
    }
  };

  STAGE(0, 0);
  __syncthreads();
  for (int kt=0; kt<nk; ++kt){
    if (kt+1 < nk) STAGE(cur^1, kt+1);
    const unsigned short* Ab = sm + cur*4096;
    const unsigned short* Bb = sm + 8192 + cur*4096;
    bf16x8 af[4], bfr[4];
    #pragma unroll
    for (int mi=0;mi<4;++mi) af[mi] = *(const bf16x8*)(Ab + (wr + mi*16 + q)*32 + g*8);
    #pragma unroll
    for (int ni=0;ni<4;++ni) bfr[ni] = *(const bf16x8*)(Bb + (wc + ni*16 + q)*32 + g*8);
    #pragma unroll
    for (int mi=0;mi<4;++mi)
      #pragma unroll
      for (int ni=0;ni<4;++ni)
        acc[mi][ni] = __builtin_amdgcn_mfma_f32_16x16x32_bf16(af[mi], bfr[ni], acc[mi][ni], 0,0,0);
    __syncthreads();
    cur ^= 1;
  }
  #pragma unroll
  for (int mi=0;mi<4;++mi)
    #pragma unroll
    for (int ni=0;ni<4;++ni)
      #pragma unroll
      for (int r=0;r<4;++r){
        int row = bm + wr + mi*16 + g*4 + r;
        int col = bn + wc + ni*16 + q;
        size_t idx = (size_t)row*N + col;
        float v = acc[mi][ni][r];
        if (EPI==0) ((unsigned short*)Cout)[idx] = f2bfu(v);
        else if (EPI==1){ float sg = v/(1.0f+__expf(-v)); ((unsigned short*)Cout)[idx] = f2bfu(sg); }
        else ((float*)Cout)[idx] = resid[idx] + v;
      }
}

// ---------------- 128x256 GEMM: BK=64, 8 waves, ring-3 + counted vmcnt (round 11, verified 766us) ----------------
template<int EPI>
__global__ __launch_bounds__(512,1)
void k_gemm2(const unsigned short* __restrict__ A, const unsigned short* __restrict__ Bw,
             void* Cout, const float* resid, int M, int N, int K){
  __shared__ __align__(16) char sm[147456];
  const int tid = threadIdx.x;
  const int wid = tid>>6, l = tid&63, g = l>>4, q = l&15;
  const int wm = wid>>2, wn = wid&3;
  // column-major XCD chunking (neutral but harmless; grids always nwg%8==0)
  const int gy = gridDim.y;
  const int orig = blockIdx.y*gridDim.x + blockIdx.x;
  const int qq = (gridDim.x*gy)>>3;
  const int nid = (orig&7)*qq + (orig>>3);
  const int bm = (nid % gy) << 7;
  const int bn = (nid / gy) << 8;
  f32x4 acc[4][4];
  #pragma unroll
  for (int a=0;a<4;++a)
    #pragma unroll
    for (int b2=0;b2<4;++b2) acc[a][b2] = f32x4{0.f,0.f,0.f,0.f};

  const unsigned short* Ag = A + (size_t)bm*K;
  const unsigned short* Bg = Bw + (size_t)bn*K;
  const int nk = K>>6;

  auto STAGE_A = [&](int buf, int kt){
    #pragma unroll
    for (int j=0;j<2;++j){
      int L = (j*512+tid)*16;
      int lr = L>>7, c8 = (L>>4)&7;
      int cg = c8 ^ (lr&7);
      int lofs = __builtin_amdgcn_readfirstlane(buf*49152 + j*8192 + wid*1024);
      gload16(Ag + (size_t)lr*K + (kt<<6) + cg*8, sm + lofs);
    }
  };
  auto STAGE_B1 = [&](int buf, int kt, int j){
    int L = (j*512+tid)*16;
    int rn = L>>7, c8 = (L>>4)&7;
    int cg = c8 ^ (rn&7);
    int lofs = __builtin_amdgcn_readfirstlane(buf*49152 + 16384 + j*8192 + wid*1024);
    gload16(Bg + (size_t)rn*K + (kt<<6) + cg*8, sm + lofs);
  };

  STAGE_A(0,0); STAGE_B1(0,0,0); STAGE_B1(0,0,1); STAGE_B1(0,0,2); STAGE_B1(0,0,3);
  STAGE_A(1,1); STAGE_B1(1,1,0); STAGE_B1(1,1,1); STAGE_B1(1,1,2); STAGE_B1(1,1,3);

  int buf = 0;
  for (int kt=0; kt<nk; ++kt){
    int p2 = buf+2; if (p2>2) p2-=3;
    if (kt+1 < nk) asm volatile("s_waitcnt vmcnt(6)" ::: "memory");
    else           asm volatile("s_waitcnt vmcnt(0)" ::: "memory");
    asm volatile("s_waitcnt lgkmcnt(0)" ::: "memory");
    __builtin_amdgcn_s_barrier();
    asm volatile("" ::: "memory");

    const char* Ab = sm + buf*49152;
    const char* Bb = sm + buf*49152 + 16384;

    #pragma unroll
    for (int ks=0; ks<2; ++ks){
      if (kt+2 < nk){
        if (ks==0){ STAGE_A(p2, kt+2); STAGE_B1(p2, kt+2, 0); }
        else      { STAGE_B1(p2, kt+2, 1); STAGE_B1(p2, kt+2, 2); STAGE_B1(p2, kt+2, 3); }
      }
      bf16x8 af[4], bfr[4];
      #pragma unroll
      for (int mi=0;mi<4;++mi){
        int lr = wm*64 + mi*16 + q;
        af[mi] = *(const bf16x8*)(Ab + lr*128 + (((ks*4+g) ^ (lr&7))<<4));
      }
      #pragma unroll
      for (int ni=0;ni<4;++ni){
        int rn = wn*64 + ni*16 + q;
        bfr[ni] = *(const bf16x8*)(Bb + rn*128 + (((ks*4+g) ^ (rn&7))<<4));
      }
      asm volatile("s_waitcnt lgkmcnt(0)" ::: "memory");
      __builtin_amdgcn_s_setprio(1);
      #pragma unroll
      for (int mi=0;mi<4;++mi)
        #pragma unroll
        for (int ni=0;ni<4;++ni)
          acc[mi][ni] = __builtin_amdgcn_mfma_f32_16x16x32_bf16(af[mi], bfr[ni], acc[mi][ni], 0,0,0);
      __builtin_amdgcn_s_setprio(0);
    }
    buf = (buf==2) ? 0 : buf+1;
  }

  #pragma unroll
  for (int mi=0;mi<4;++mi)
    #pragma unroll
    for (int ni=0;ni<4;++ni)
      #pragma unroll
      for (int r=0;r<4;++r){
        int row = bm + wm*64 + mi*16 + g*4 + r;
        int col = bn + wn*64 + ni*16 + q;
        size_t idx = (size_t)row*N + col;
        float v = acc[mi][ni][r];
        if (EPI==0) ((unsigned short*)Cout)[idx] = f2bfu(v);
        else if (EPI==1){ float sg = v/(1.0f+__expf(-v)); ((unsigned short*)Cout)[idx] = f2bfu(sg); }
        else ((float*)Cout)[idx] = resid[idx] + v;
      }
}

// ---------------- self QKV postprocess: QK-norm + RoPE; V -> transposed layout ----------------
__global__ void k_self_pp(const unsigned short* __restrict__ qkv, const float* __restrict__ fc,
                          const float* __restrict__ fs, const float* __restrict__ qn,
                          const float* __restrict__ kn,
                          unsigned short* __restrict__ Qb, unsigned short* __restrict__ Kb,
                          unsigned short* __restrict__ Vt){
  const int row = blockIdx.x;           // b*2048 + s
  const int b = row>>11, s = row&2047;
  const int w = threadIdx.x>>6, l = threadIdx.x&63;
  const int d0 = 2*l, d1 = d0+1;
  const float c0 = fc[s*128+d0], c1 = fc[s*128+d1];
  const float s0 = fs[s*128+d0], s1 = fs[s*128+d1];
  #pragma unroll
  for (int it=0; it<6; ++it){
    const int hh = it*4 + w;
    const unsigned short* src = qkv + (size_t)row*3072 + hh*128;
    if (hh >= 20){
      const int hv = hh - 20;
      size_t base = ((size_t)(b*4 + hv))*128*2048;
      Vt[base + (size_t)d0*2048 + s] = src[d0];
      Vt[base + (size_t)d1*2048 + s] = src[d1];
    } else {
      float x0 = bf2f(src[d0]), x1 = bf2f(src[d1]);
      float ss = x0*x0 + x1*x1;
      #pragma unroll
      for (int o=32;o;o>>=1) ss += __shfl_xor(ss, o);
      float rs = rsqrtf(ss*(1.0f/128.0f) + EPS);
      if (hh < 16){
        float y0 = x0*rs*qn[d0], y1 = x1*rs*qn[d1];
        *(unsigned*)(Qb + (((size_t)(b*16 + hh)*2048 + s)*128) + d0)
          = pack2((y0*c0 - y1*s0)*SC2L, (y1*c1 + y0*s1)*SC2L);
      } else {
        float y0 = x0*rs*kn[d0], y1 = x1*rs*kn[d1];
        *(unsigned*)(Kb + (((size_t)(b*4 + (hh-16))*2048 + s)*128) + d0)
          = pack2(y0*c0 - y1*s0, y1*c1 + y0*s1);
      }
    }
  }
}

// ---------------- cross Q postprocess: RoPE FIRST then rmsnorm (Q scaled by SC2L) ----------------
__global__ void k_crossq_pp(const unsigned short* __restrict__ qc, const float* __restrict__ fc,
                            const float* __restrict__ fs, const float* __restrict__ qn,
                            unsigned short* __restrict__ Qb){
  const int row = blockIdx.x;
  const int b = row>>11, s = row&2047;
  const int w = threadIdx.x>>6, l = threadIdx.x&63;
  const int d0 = 2*l, d1 = d0+1;
  const float c0 = fc[s*128+d0], c1 = fc[s*128+d1];
  const float s0 = fs[s*128+d0], s1 = fs[s*128+d1];
  #pragma unroll
  for (int it=0; it<4; ++it){
    const int hh = it*4 + w;
    const unsigned short* src = qc + (size_t)row*2048 + hh*128;
    float x0 = bf2f(src[d0]), x1 = bf2f(src[d1]);
    float y0 = x0*c0 - x1*s0;
    float y1 = x1*c1 + x0*s1;
    float ss = y0*y0 + y1*y1;
    #pragma unroll
    for (int o=32;o;o>>=1) ss += __shfl_xor(ss, o);
    float rs = rsqrtf(ss*(1.0f/128.0f) + EPS);
    *(unsigned*)(Qb + (((size_t)(b*16 + hh)*2048 + s)*128) + d0)
      = pack2(y0*rs*qn[d0]*SC2L, y1*rs*qn[d1]*SC2L);
  }
}

// ---------------- cross KV postprocess: K rmsnorm (no rope); V transposed copy ----------------
__global__ void k_crosskv_pp(const unsigned short* __restrict__ kvc, const float* __restrict__ kn,
                             unsigned short* __restrict__ Kb, unsigned short* __restrict__ Vt){
  const int row = blockIdx.x;           // b*2048 + sctx
  const int b = row>>11, s = row&2047;
  const int w = threadIdx.x>>6, l = threadIdx.x&63;
  const int d0 = 2*l, d1 = d0+1;
  #pragma unroll
  for (int it=0; it<2; ++it){
    const int hh = it*4 + w;
    const unsigned short* src = kvc + (size_t)row*1024 + hh*128;
    if (hh < 4){
      float x0 = bf2f(src[d0]), x1 = bf2f(src[d1]);
      float ss = x0*x0 + x1*x1;
      #pragma unroll
      for (int o=32;o;o>>=1) ss += __shfl_xor(ss, o);
      float rs = rsqrtf(ss*(1.0f/128.0f) + EPS);
      *(unsigned*)(Kb + (((size_t)(b*4 + hh)*2048 + s)*128) + d0)
        = pack2(x0*rs*kn[d0], x1*rs*kn[d1]);
    } else {
      const int hv = hh-4;
      size_t base = ((size_t)(b*4 + hv))*128*2048;
      Vt[base + (size_t)d0*2048 + s] = src[d0];
      Vt[base + (size_t)d1*2048 + s] = src[d1];
    }
  }
}

// ---------------- flash attention, GQA head-fused, ROUND 13: 512-thread blocks, 512-block grid ----------------
// Grid 64x4x2 = 512 blocks -> 2 blocks/CU (LDS 56KB): cross-block overlap hides the
// per-tile stage drain (single K/V buffer; dbuf dropped to fit 2 blocks). 8 waves:
// wave w -> head hq=w>>1, q-rows (w&1)*16+q of the 32-row qt tile. Per-wave math,
// swizzles, log2 softmax identical to round 9.
// LDS: K[0,16K) V[16K,32K) P[32K,48K: 8 waves x 2K) bias[48K,56K)
template<bool QMASK>
__global__ __launch_bounds__(512,4)
void k_attn(const unsigned short* __restrict__ Qg, const unsigned short* __restrict__ Kg,
            const unsigned short* __restrict__ Vtg,
            const unsigned char* __restrict__ qm, const unsigned char* __restrict__ km,
            unsigned short* __restrict__ Og, int H, int HKV){
  constexpr int SK = 2048, SQ = 2048, NT = SK/64;
  __shared__ __align__(16) char smem[57344];
  const int qt = blockIdx.x, hk = blockIdx.y, b = blockIdx.z;
  const int REP = H/HKV;
  const int tid = threadIdx.x, w = tid>>6, l = tid&63, g = l>>4, q = l&15;
  const int hq = w>>1, wsub = w&1;

  if (tid < 256){ // build f32 mask-bias table (0 visible, -3e38 masked)
    const unsigned long long mv = ((const unsigned long long*)(km + (size_t)b*SK))[tid];
    float* bl = (float*)(smem + 49152);
    #pragma unroll
    for (int j=0;j<8;++j)
      bl[tid*8+j] = ((mv>>(8*j)) & 0xffull) ? 0.0f : -3.0e38f;
  }

  const int h = hk*REP + hq;
  const size_t qrow = (size_t)(b*H + h)*SQ + qt*32 + wsub*16 + q;
  bf16x8 qf[4];
  #pragma unroll
  for (int ks=0;ks<4;++ks) qf[ks] = *(const bf16x8*)(Qg + qrow*128 + ks*32 + g*8);

  f32x4 oacc[8];
  #pragma unroll
  for (int i=0;i<8;++i) oacc[i] = f32x4{0.f,0.f,0.f,0.f};
  float m_run = -1.0e30f, l_run = 0.f;

  const unsigned short* Kt0 = Kg + (size_t)(b*HKV + hk)*SK*128;
  const unsigned short* Vt0 = Vtg + (size_t)(b*HKV + hk)*128*SK;
  const float* biasf = (const float*)(smem + 49152);
  char* Pl = smem + 32768 + w*2048;

  // stage one 64x128 K tile + 128x64 Vt tile with 512 threads: 2 gload16 each side
  auto STAGE_T = [&](int t){
    #pragma unroll
    for (int j=0;j<2;++j){ // K: chunk idx = j*512+tid; row r=idx>>4, chunk c16=idx&15
      int idx = j*512 + tid;
      int r = idx>>4, c16 = idx&15;
      int c = (c16 & 8) | ((c16 & 7) ^ (r & 7));
      int lofs = __builtin_amdgcn_readfirstlane(j*8192 + w*1024);
      gload16(Kt0 + (size_t)(t*64 + r)*128 + c*8, smem + lofs);
    }
    #pragma unroll
    for (int j=0;j<2;++j){ // Vt: chunk idx = j*512+tid; d=idx>>3, chunk c8=idx&7
      int idx = j*512 + tid;
      int d = idx>>3, c8 = idx&7;
      int c = c8 ^ (d & 7);
      int lofs = __builtin_amdgcn_readfirstlane(16384 + j*8192 + w*1024);
      gload16(Vt0 + (size_t)d*SK + t*64 + c*8, smem + lofs);
    }
  };

  for (int t=0; t<NT; ++t){
    asm volatile("s_waitcnt lgkmcnt(0)" ::: "memory");   // my reads of tile t-1 retired
    __builtin_amdgcn_s_barrier();                        // (also covers bias-table writes at t=0)
    asm volatile("" ::: "memory");
    STAGE_T(t);
    asm volatile("s_waitcnt vmcnt(0)" ::: "memory");
    __builtin_amdgcn_s_barrier();
    asm volatile("" ::: "memory");

    const char* Kb_ = smem;
    const char* Vb_ = smem + 16384;

    // S^T = K . Q (log2 domain)
    f32x4 sacc[4];
    #pragma unroll
    for (int i=0;i<4;++i) sacc[i] = f32x4{0.f,0.f,0.f,0.f};
    __builtin_amdgcn_s_setprio(1);
    #pragma unroll
    for (int ks=0;ks<4;++ks){
      #pragma unroll
      for (int mi=0;mi<4;++mi){
        int kcol = mi*16 + q;
        int c = 4*ks + g;
        int c16 = (c & 8) | ((c & 7) ^ (kcol & 7));
        bf16x8 ak = *(const bf16x8*)(Kb_ + kcol*256 + c16*16);
        sacc[mi] = __builtin_amdgcn_mfma_f32_16x16x32_bf16(ak, qf[ks], sacc[mi], 0,0,0);
      }
    }
    __builtin_amdgcn_s_setprio(0);

    // online softmax (log2) + mask bias + defer-max
    float sv[4][4];
    float mloc = -3.0e38f;
    #pragma unroll
    for (int mi=0;mi<4;++mi){
      f32x4 bb = *(const f32x4*)(biasf + t*64 + mi*16 + g*4);
      #pragma unroll
      for (int r=0;r<4;++r){
        float v = sacc[mi][r] + bb[r];
        sv[mi][r] = v;
        mloc = fmaxf(mloc, v);
      }
    }
    mloc = fmaxf(mloc, __shfl_xor(mloc, 16));
    mloc = fmaxf(mloc, __shfl_xor(mloc, 32));
    if (!__all(mloc - m_run <= 8.0f)){
      float mnew = fmaxf(m_run, mloc);
      float alpha = exp2a(m_run - mnew);
      l_run *= alpha;
      #pragma unroll
      for (int i=0;i<8;++i) oacc[i] *= alpha;
      m_run = mnew;
    }
    float rsum = 0.f;
    unsigned pb[4][2];
    #pragma unroll
    for (int mi=0;mi<4;++mi){
      float p0 = exp2a(sv[mi][0] - m_run);
      float p1 = exp2a(sv[mi][1] - m_run);
      float p2 = exp2a(sv[mi][2] - m_run);
      float p3 = exp2a(sv[mi][3] - m_run);
      rsum += (p0+p1)+(p2+p3);
      pb[mi][0] = cvtpk(p0, p1);
      pb[mi][1] = cvtpk(p2, p3);
    }
    rsum += __shfl_xor(rsum, 16);
    rsum += __shfl_xor(rsum, 32);
    l_run += rsum;

    // P -> wave-private LDS (XOR chunk swizzle)
    #pragma unroll
    for (int mi=0;mi<4;++mi){
      int c16 = (2*mi + (g>>1)) ^ (q & 7);
      uint2 uu; uu.x = pb[mi][0]; uu.y = pb[mi][1];
      *(uint2*)(Pl + q*128 + c16*16 + (g&1)*8) = uu;
    }
    asm volatile("" ::: "memory");

    // O^T += Vt . P^T
    __builtin_amdgcn_s_setprio(1);
    #pragma unroll
    for (int ks=0;ks<2;++ks){
      int c16 = (4*ks + g) ^ (q & 7);
      bf16x8 pf = *(const bf16x8*)(Pl + q*128 + c16*16);
      #pragma unroll
      for (int mi=0;mi<8;++mi){
        int d = mi*16 + q;
        bf16x8 vf = *(const bf16x8*)(Vb_ + d*128 + c16*16);
        oacc[mi] = __builtin_amdgcn_mfma_f32_16x16x32_bf16(vf, pf, oacc[mi], 0,0,0);
      }
    }
    __builtin_amdgcn_s_setprio(0);
  }

  float inv = (l_run > 0.f) ? 1.0f/l_run : 0.f;
  if (QMASK){
    if (!qm[(size_t)b*SQ + qt*32 + wsub*16 + q]) inv = 0.f;
  }
  // per-head transpose + store, 4 sequential phases
  float* Ot = (float*)smem;               // [128][33] f32 = 16,896 B
  const int qloc = tid>>4, seg = tid&15;
  #pragma unroll
  for (int ph=0; ph<4; ++ph){
    __syncthreads();
    if (hq == ph){
      #pragma unroll
      for (int mi=0;mi<8;++mi)
        #pragma unroll
        for (int r=0;r<4;++r){
          int d = mi*16 + g*4 + r;
          Ot[d*33 + wsub*16 + q] = oacc[mi][r]*inv;
        }
    }
    __syncthreads();
    int srow = qt*32 + qloc;
    size_t obase = ((size_t)b*SQ + srow)*(size_t)(H*128) + (size_t)(hk*REP + ph)*128 + seg*8;
    float vv[8];
    #pragma unroll
    for (int j=0;j<8;++j) vv[j] = Ot[(seg*8 + j)*33 + qloc];
    uint4 u;
    u.x = pack2(vv[0],vv[1]); u.y = pack2(vv[2],vv[3]);
    u.z = pack2(vv[4],vv[5]); u.w = pack2(vv[6],vv[7]);
    *(uint4*)(Og + obase) = u;
  }
}

// ---------------- launch ----------------
extern "C" void kernel_launch(void* const* d_in, const int* in_sizes, int n_in,
                              void* d_out, int out_size, void* d_ws, size_t ws_size,
                              hipStream_t stream){
  const float* x        = (const float*)d_in[0];
  const float* ctx      = (const float*)d_in[1];
  const float* fc       = (const float*)d_in[2];
  const float* fs       = (const float*)d_in[3];
  const float* wqkv     = (const float*)d_in[4];
  const float* wo_self  = (const float*)d_in[5];
  const float* qn_self  = (const float*)d_in[6];
  const float* kn_self  = (const float*)d_in[7];
  const float* wq       = (const float*)d_in[8];
  const float* wkv      = (const float*)d_in[9];
  const float* wo_cross = (const float*)d_in[10];
  const float* qn_cross = (const float*)d_in[11];
  const float* kn_cross = (const float*)d_in[12];
  const float* w1       = (const float*)d_in[13];
  const float* w2       = (const float*)d_in[14];
  const float* attn_nw  = (const float*)d_in[15];
  const float* cross_nw = (const float*)d_in[16];
  const float* ffn_nw   = (const float*)d_in[17];
  const unsigned* vis_raw   = (const unsigned*)d_in[18];
  const unsigned* cmask_raw = (const unsigned*)d_in[19];
  float* out = (float*)d_out;

  // HID padded 5464 -> 5632 (divisible by 256) for the new GEMM; zero-pad keeps exactness.
  char* ws = (char*)d_ws;
  unsigned short* wslot = (unsigned short*)(ws);               // 23,068,672 B (5632x2048 bf16)
  unsigned short* ctxbf = (unsigned short*)(ws +  23068672);   // 16,777,216
  unsigned short* nbuf  = (unsigned short*)(ws +  39845888);   // 16,777,216
  unsigned short* qkvb  = (unsigned short*)(ws +  56623104);   // 25,165,824
  unsigned short* Qb    = (unsigned short*)(ws +  81788928);   // 16,777,216
  unsigned short* Kb    = (unsigned short*)(ws +  98566144);   //  4,194,304
  unsigned short* Vtb   = (unsigned short*)(ws + 102760448);   //  4,194,304
  unsigned short* aob   = (unsigned short*)(ws + 106954752);   // aliased with midb (aob dead before w1)
  unsigned short* midb  = (unsigned short*)(ws + 106954752);   // 46,137,344 (4096x5632 bf16)
  unsigned char*  visN  = (unsigned char*)(ws + 153092096);    //  4,096
  unsigned char*  cmkN  = (unsigned char*)(ws + 153096192);    //  4,096 -> end 153,100,288
  unsigned short* qcb   = qkvb;                                // cross-q reuses qkv buffer
  unsigned short* kvcb  = qkvb + 8388608;                      // +16,777,216 B

  auto conv = [&](const float* s, unsigned short* dst, size_t n){
    int n4 = (int)(n>>2);
    k_conv<<<(n4+255)/256, 256, 0, stream>>>(s, dst, n4);
  };

  // ---- canonicalize masks (bool-as-bytes vs bool-as-int32) ----
  k_masknorm<<<1,256,0,stream>>>(vis_raw, cmask_raw, visN, cmkN);

  // ---- self attention path ----
  conv(ctx, ctxbf, (size_t)4096*2048);
  k_rms<<<4096,256,0,stream>>>(x, attn_nw, nbuf);
  conv(wqkv, wslot, (size_t)3072*2048);
  k_gemm2<0><<<dim3(12,32),512,0,stream>>>(nbuf, wslot, qkvb, nullptr, 4096,3072,2048);
  k_self_pp<<<4096,256,0,stream>>>(qkvb, fc, fs, qn_self, kn_self, Qb, Kb, Vtb);
  k_attn<true><<<dim3(64,4,2),512,0,stream>>>(Qb, Kb, Vtb, visN, visN, aob, 16, 4);
  conv(wo_self, wslot, (size_t)2048*2048);
  k_gemm2<2><<<dim3(8,32),512,0,stream>>>(aob, wslot, out, x, 4096,2048,2048);

  // ---- cross attention path ----
  k_rms<<<4096,256,0,stream>>>(out, cross_nw, nbuf);
  conv(wq, wslot, (size_t)2048*2048);
  k_gemm2<0><<<dim3(8,32),512,0,stream>>>(nbuf, wslot, qcb, nullptr, 4096,2048,2048);
  conv(wkv, wslot, (size_t)1024*2048);
  k_gemm<0><<<dim3(8,32),256,0,stream>>>(ctxbf, wslot, kvcb, nullptr, 4096,1024,2048);
  k_crossq_pp<<<4096,256,0,stream>>>(qcb, fc, fs, qn_cross, Qb);
  k_crosskv_pp<<<4096,256,0,stream>>>(kvcb, kn_cross, Kb, Vtb);
  k_attn<false><<<dim3(64,4,2),512,0,stream>>>(Qb, Kb, Vtb, nullptr, cmkN, aob, 16, 4);
  conv(wo_cross, wslot, (size_t)2048*2048);
  k_gemm2<2><<<dim3(8,32),512,0,stream>>>(aob, wslot, out, out, 4096,2048,2048);

  // ---- FFN (silu MLP), HID padded 5464 -> 5632 ----
  k_rms<<<4096,256,0,stream>>>(out, ffn_nw, nbuf);
  k_convpad_rows<<<(5632*2048/4+255)/256,256,0,stream>>>(w1, wslot, 5464, 2048, 5632);
  k_gemm2<1><<<dim3(22,32),512,0,stream>>>(nbuf, wslot, midb, nullptr, 4096,5632,2048);
  k_convpad_cols<<<(2048*5632/4+255)/256,256,0,stream>>>(w2, wslot, 2048, 5464, 5632);
  k_gemm2<2><<<dim3(8,32),512,0,stream>>>(midb, wslot, out, out, 4096,2048,5632);

  (void)in_sizes; (void)n_in; (void)out_size; (void)ws_size;
}

// Round 14
// 763.736 us; speedup vs baseline: 1.0434x; 1.0102x over previous
//
#include <hip/hip_runtime.h>

#define DEVI __device__ __forceinline__

typedef __attribute__((ext_vector_type(4))) float f32x4;
typedef __attribute__((ext_vector_type(8))) __bf16 bf16x8;

static constexpr float EPS = 1.1920929e-07f;
// SCALE(1/sqrt(128)) * log2(e): folded into Q so QK^T scores are log2-domain
static constexpr float SC2L = 0.12751551960234575f;

DEVI float bf2f(unsigned short u){ return __uint_as_float(((unsigned)u)<<16); }
DEVI unsigned short f2bfu(float f){
  unsigned u = __float_as_uint(f);
  u += 0x7fffu + ((u>>16)&1u);
  return (unsigned short)(u>>16);
}
DEVI unsigned pack2(float a, float b){ return (unsigned)f2bfu(a) | ((unsigned)f2bfu(b)<<16); }
DEVI float exp2a(float x){ float r; asm("v_exp_f32 %0, %1" : "=v"(r) : "v"(x)); return r; }
DEVI unsigned cvtpk(float lo, float hi){
  unsigned r; asm("v_cvt_pk_bf16_f32 %0, %1, %2" : "=v"(r) : "v"(lo), "v"(hi)); return r;
}

DEVI void gload16(const void* g, const void* l){
  __builtin_amdgcn_global_load_lds((const __attribute__((address_space(1))) void*)g,
                                   (__attribute__((address_space(3))) void*)l, 16, 0, 0);
}

// ---------------- mask normalization: detect bool-as-bytes vs bool-as-int32 ----------------
__global__ void k_masknorm(const unsigned* __restrict__ vin, const unsigned* __restrict__ cin,
                           unsigned char* __restrict__ vout, unsigned char* __restrict__ cout){
  __shared__ int smode;
  const int t = threadIdx.x;
  if (t==0) smode = 0;
  __syncthreads();
  unsigned loc = 0;
  for (int i=t; i<1024; i+=256) loc |= (vin[i] > 1u);
  if (loc) smode = 1;              // benign race: all writers store 1
  __syncthreads();
  if (smode){                      // byte layout: plain copy (4096 B each)
    for (int i=t; i<1024; i+=256){
      ((unsigned*)vout)[i] = vin[i];
      ((unsigned*)cout)[i] = cin[i];
    }
  } else {                         // int32 layout: compress to bytes
    const int* vi = (const int*)vin; const int* ci = (const int*)cin;
    for (int i=t; i<4096; i+=256){
      vout[i] = (unsigned char)(vi[i] != 0);
      cout[i] = (unsigned char)(ci[i] != 0);
    }
  }
}

// ---------------- converters ----------------
__global__ void k_conv(const float* __restrict__ s, unsigned short* __restrict__ d, int n4){
  int i = blockIdx.x*256 + threadIdx.x;
  if (i >= n4) return;
  float4 v = ((const float4*)s)[i];
  uint2 u; u.x = pack2(v.x, v.y); u.y = pack2(v.z, v.w);
  ((uint2*)d)[i] = u;
}
// w1: [R][C] -> [Rp][C], pad rows with zero
__global__ void k_convpad_rows(const float* __restrict__ s, unsigned short* __restrict__ d,
                               int R, int C, int Rp){
  int i = blockIdx.x*256 + threadIdx.x;
  int total = (Rp*C)>>2;
  if (i >= total) return;
  uint2 u; u.x = 0u; u.y = 0u;
  if (i*4 < R*C){ float4 v = ((const float4*)s)[i]; u.x = pack2(v.x,v.y); u.y = pack2(v.z,v.w); }
  ((uint2*)d)[i] = u;
}
// w2: [N][K] -> [N][Kp], pad inner (K) with zero
__global__ void k_convpad_cols(const float* __restrict__ s, unsigned short* __restrict__ d,
                               int N, int K, int Kp){
  int i = blockIdx.x*256 + threadIdx.x;
  int total = (N*Kp)>>2;
  if (i >= total) return;
  int i4 = i*4; int n = i4/Kp; int k = i4 - n*Kp;
  uint2 u; u.x = 0u; u.y = 0u;
  if (k < K){ float4 v = *(const float4*)(s + (size_t)n*K + k); u.x = pack2(v.x,v.y); u.y = pack2(v.z,v.w); }
  ((uint2*)d)[i] = u;
}

// ---------------- rmsnorm over rows of 2048, fp32 in -> bf16 out ----------------
__global__ void k_rms(const float* __restrict__ X, const float* __restrict__ W,
                      unsigned short* __restrict__ Y){
  const int row = blockIdx.x, tid = threadIdx.x;
  const float* x = X + (size_t)row*2048;
  float4 v0 = ((const float4*)x)[tid*2];
  float4 v1 = ((const float4*)x)[tid*2+1];
  float ss = v0.x*v0.x+v0.y*v0.y+v0.z*v0.z+v0.w*v0.w
           + v1.x*v1.x+v1.y*v1.y+v1.z*v1.z+v1.w*v1.w;
  #pragma unroll
  for (int o=32;o;o>>=1) ss += __shfl_xor(ss, o);
  __shared__ float red[4];
  if ((tid&63)==0) red[tid>>6] = ss;
  __syncthreads();
  float tot = red[0]+red[1]+red[2]+red[3];
  float rs = rsqrtf(tot*(1.0f/2048.0f) + EPS);
  float4 w0 = ((const float4*)W)[tid*2];
  float4 w1 = ((const float4*)W)[tid*2+1];
  uint4 u;
  u.x = pack2(v0.x*rs*w0.x, v0.y*rs*w0.y);
  u.y = pack2(v0.z*rs*w0.z, v0.w*rs*w0.w);
  u.z = pack2(v1.x*rs*w1.x, v1.y*rs*w1.y);
  u.w = pack2(v1.z*rs*w1.z, v1.w*rs*w1.w);
  *(uint4*)(Y + (size_t)row*2048 + tid*8) = u;
}

// ---------------- legacy GEMM (m97 structure), used for wkv only ----------------
template<int EPI>
__global__ void k_gemm(const unsigned short* __restrict__ A, const unsigned short* __restrict__ Bw,
                       void* Cout, const float* resid, int M, int N, int K){
  __shared__ __align__(16) unsigned short sm[16384];
  const int tid = threadIdx.x;
  const int w = tid>>6, l = tid&63, g = l>>4, q = l&15;
  const int bm = blockIdx.y<<7, bn = blockIdx.x<<7;
  const int wr = (w>>1)<<6, wc = (w&1)<<6;
  f32x4 acc[4][4];
  #pragma unroll
  for (int a=0;a<4;++a)
    #pragma unroll
    for (int b2=0;b2<4;++b2) acc[a][b2] = f32x4{0.f,0.f,0.f,0.f};

  const unsigned short* Ag = A + (size_t)bm*K;
  const unsigned short* Bg = Bw + (size_t)bn*K;
  const int nk = K>>5;
  int cur = 0;

  auto STAGE = [&](int buf, int kt){
    #pragma unroll
    for (int i=0;i<2;++i){
      int L = (i*256+tid)*16;
      int r = L>>6; int ce = (L&63)>>1;
      int lofs = __builtin_amdgcn_readfirstlane(buf*8192 + i*4096 + (tid>>6)*1024);
      gload16(Ag + (size_t)r*K + (kt<<5) + ce, (const char*)sm + lofs);
    }
    #pragma unroll
    for (int i=0;i<2;++i){
      int L = (i*256+tid)*16;
      int r = L>>6; int ce = (L&63)>>1;
      int lofs = __builtin_amdgcn_readfirstlane(16384 + buf*8192 + i*4096 + (tid>>6)*1024);
      gload16(Bg + (size_t)r*K + (kt<<5) + ce, (const char*)sm + lofs);
    }
  };

  STAGE(0, 0);
  __syncthreads();
  for (int kt=0; kt<nk; ++kt){
    if (kt+1 < nk) STAGE(cur^1, kt+1);
    const unsigned short* Ab = sm + cur*4096;
    const unsigned short* Bb = sm + 8192 + cur*4096;
    bf16x8 af[4], bfr[4];
    #pragma unroll
    for (int mi=0;mi<4;++mi) af[mi] = *(const bf16x8*)(Ab + (wr + mi*16 + q)*32 + g*8);
    #pragma unroll
    for (int ni=0;ni<4;++ni) bfr[ni] = *(const bf16x8*)(Bb + (wc + ni*16 + q)*32 + g*8);
    #pragma unroll
    for (int mi=0;mi<4;++mi)
      #pragma unroll
      for (int ni=0;ni<4;++ni)
        acc[mi][ni] = __builtin_amdgcn_mfma_f32_16x16x32_bf16(af[mi], bfr[ni], acc[mi][ni], 0,0,0);
    __syncthreads();
    cur ^= 1;
  }
  #pragma unroll
  for (int mi=0;mi<4;++mi)
    #pragma unroll
    for (int ni=0;ni<4;++ni)
      #pragma unroll
      for (int r=0;r<4;++r){
        int row = bm + wr + mi*16 + g*4 + r;
        int col = bn + wc + ni*16 + q;
        size_t idx = (size_t)row*N + col;
        float v = acc[mi][ni][r];
        if (EPI==0) ((unsigned short*)Cout)[idx] = f2bfu(v);
        else if (EPI==1){ float sg = v/(1.0f+__expf(-v)); ((unsigned short*)Cout)[idx] = f2bfu(sg); }
        else ((float*)Cout)[idx] = resid[idx] + v;
      }
}

// ---------------- 128x256 GEMM: BK=64, 8 waves, ring-3 + counted vmcnt (round 11, verified 766us) ----------------
template<int EPI>
__global__ __launch_bounds__(512,1)
void k_gemm2(const unsigned short* __restrict__ A, const unsigned short* __restrict__ Bw,
             void* Cout, const float* resid, int M, int N, int K){
  __shared__ __align__(16) char sm[147456];
  const int tid = threadIdx.x;
  const int wid = tid>>6, l = tid&63, g = l>>4, q = l&15;
  const int wm = wid>>2, wn = wid&3;
  // column-major XCD chunking (neutral but harmless; grids always nwg%8==0)
  const int gy = gridDim.y;
  const int orig = blockIdx.y*gridDim.x + blockIdx.x;
  const int qq = (gridDim.x*gy)>>3;
  const int nid = (orig&7)*qq + (orig>>3);
  const int bm = (nid % gy) << 7;
  const int bn = (nid / gy) << 8;
  f32x4 acc[4][4];
  #pragma unroll
  for (int a=0;a<4;++a)
    #pragma unroll
    for (int b2=0;b2<4;++b2) acc[a][b2] = f32x4{0.f,0.f,0.f,0.f};

  const unsigned short* Ag = A + (size_t)bm*K;
  const unsigned short* Bg = Bw + (size_t)bn*K;
  const int nk = K>>6;

  auto STAGE_A = [&](int buf, int kt){
    #pragma unroll
    for (int j=0;j<2;++j){
      int L = (j*512+tid)*16;
      int lr = L>>7, c8 = (L>>4)&7;
      int cg = c8 ^ (lr&7);
      int lofs = __builtin_amdgcn_readfirstlane(buf*49152 + j*8192 + wid*1024);
      gload16(Ag + (size_t)lr*K + (kt<<6) + cg*8, sm + lofs);
    }
  };
  auto STAGE_B1 = [&](int buf, int kt, int j){
    int L = (j*512+tid)*16;
    int rn = L>>7, c8 = (L>>4)&7;
    int cg = c8 ^ (rn&7);
    int lofs = __builtin_amdgcn_readfirstlane(buf*49152 + 16384 + j*8192 + wid*1024);
    gload16(Bg + (size_t)rn*K + (kt<<6) + cg*8, sm + lofs);
  };

  STAGE_A(0,0); STAGE_B1(0,0,0); STAGE_B1(0,0,1); STAGE_B1(0,0,2); STAGE_B1(0,0,3);
  STAGE_A(1,1); STAGE_B1(1,1,0); STAGE_B1(1,1,1); STAGE_B1(1,1,2); STAGE_B1(1,1,3);

  int buf = 0;
  for (int kt=0; kt<nk; ++kt){
    int p2 = buf+2; if (p2>2) p2-=3;
    if (kt+1 < nk) asm volatile("s_waitcnt vmcnt(6)" ::: "memory");
    else           asm volatile("s_waitcnt vmcnt(0)" ::: "memory");
    asm volatile("s_waitcnt lgkmcnt(0)" ::: "memory");
    __builtin_amdgcn_s_barrier();
    asm volatile("" ::: "memory");

    const char* Ab = sm + buf*49152;
    const char* Bb = sm + buf*49152 + 16384;

    #pragma unroll
    for (int ks=0; ks<2; ++ks){
      if (kt+2 < nk){
        if (ks==0){ STAGE_A(p2, kt+2); STAGE_B1(p2, kt+2, 0); }
        else      { STAGE_B1(p2, kt+2, 1); STAGE_B1(p2, kt+2, 2); STAGE_B1(p2, kt+2, 3); }
      }
      bf16x8 af[4], bfr[4];
      #pragma unroll
      for (int mi=0;mi<4;++mi){
        int lr = wm*64 + mi*16 + q;
        af[mi] = *(const bf16x8*)(Ab + lr*128 + (((ks*4+g) ^ (lr&7))<<4));
      }
      #pragma unroll
      for (int ni=0;ni<4;++ni){
        int rn = wn*64 + ni*16 + q;
        bfr[ni] = *(const bf16x8*)(Bb + rn*128 + (((ks*4+g) ^ (rn&7))<<4));
      }
      asm volatile("s_waitcnt lgkmcnt(0)" ::: "memory");
      __builtin_amdgcn_s_setprio(1);
      #pragma unroll
      for (int mi=0;mi<4;++mi)
        #pragma unroll
        for (int ni=0;ni<4;++ni)
          acc[mi][ni] = __builtin_amdgcn_mfma_f32_16x16x32_bf16(af[mi], bfr[ni], acc[mi][ni], 0,0,0);
      __builtin_amdgcn_s_setprio(0);
    }
    buf = (buf==2) ? 0 : buf+1;
  }

  #pragma unroll
  for (int mi=0;mi<4;++mi)
    #pragma unroll
    for (int ni=0;ni<4;++ni)
      #pragma unroll
      for (int r=0;r<4;++r){
        int row = bm + wm*64 + mi*16 + g*4 + r;
        int col = bn + wn*64 + ni*16 + q;
        size_t idx = (size_t)row*N + col;
        float v = acc[mi][ni][r];
        if (EPI==0) ((unsigned short*)Cout)[idx] = f2bfu(v);
        else if (EPI==1){ float sg = v/(1.0f+__expf(-v)); ((unsigned short*)Cout)[idx] = f2bfu(sg); }
        else ((float*)Cout)[idx] = resid[idx] + v;
      }
}

// ---------------- self QKV postprocess: QK-norm + RoPE; V -> transposed layout ----------------
__global__ void k_self_pp(const unsigned short* __restrict__ qkv, const float* __restrict__ fc,
                          const float* __restrict__ fs, const float* __restrict__ qn,
                          const float* __restrict__ kn,
                          unsigned short* __restrict__ Qb, unsigned short* __restrict__ Kb,
                          unsigned short* __restrict__ Vt){
  const int row = blockIdx.x;           // b*2048 + s
  const int b = row>>11, s = row&2047;
  const int w = threadIdx.x>>6, l = threadIdx.x&63;
  const int d0 = 2*l, d1 = d0+1;
  const float c0 = fc[s*128+d0], c1 = fc[s*128+d1];
  const float s0 = fs[s*128+d0], s1 = fs[s*128+d1];
  #pragma unroll
  for (int it=0; it<6; ++it){
    const int hh = it*4 + w;
    const unsigned short* src = qkv + (size_t)row*3072 + hh*128;
    if (hh >= 20){
      const int hv = hh - 20;
      size_t base = ((size_t)(b*4 + hv))*128*2048;
      Vt[base + (size_t)d0*2048 + s] = src[d0];
      Vt[base + (size_t)d1*2048 + s] = src[d1];
    } else {
      float x0 = bf2f(src[d0]), x1 = bf2f(src[d1]);
      float ss = x0*x0 + x1*x1;
      #pragma unroll
      for (int o=32;o;o>>=1) ss += __shfl_xor(ss, o);
      float rs = rsqrtf(ss*(1.0f/128.0f) + EPS);
      if (hh < 16){
        float y0 = x0*rs*qn[d0], y1 = x1*rs*qn[d1];
        *(unsigned*)(Qb + (((size_t)(b*16 + hh)*2048 + s)*128) + d0)
          = pack2((y0*c0 - y1*s0)*SC2L, (y1*c1 + y0*s1)*SC2L);
      } else {
        float y0 = x0*rs*kn[d0], y1 = x1*rs*kn[d1];
        *(unsigned*)(Kb + (((size_t)(b*4 + (hh-16))*2048 + s)*128) + d0)
          = pack2(y0*c0 - y1*s0, y1*c1 + y0*s1);
      }
    }
  }
}

// ---------------- cross Q postprocess: RoPE FIRST then rmsnorm (Q scaled by SC2L) ----------------
__global__ void k_crossq_pp(const unsigned short* __restrict__ qc, const float* __restrict__ fc,
                            const float* __restrict__ fs, const float* __restrict__ qn,
                            unsigned short* __restrict__ Qb){
  const int row = blockIdx.x;
  const int b = row>>11, s = row&2047;
  const int w = threadIdx.x>>6, l = threadIdx.x&63;
  const int d0 = 2*l, d1 = d0+1;
  const float c0 = fc[s*128+d0], c1 = fc[s*128+d1];
  const float s0 = fs[s*128+d0], s1 = fs[s*128+d1];
  #pragma unroll
  for (int it=0; it<4; ++it){
    const int hh = it*4 + w;
    const unsigned short* src = qc + (size_t)row*2048 + hh*128;
    float x0 = bf2f(src[d0]), x1 = bf2f(src[d1]);
    float y0 = x0*c0 - x1*s0;
    float y1 = x1*c1 + x0*s1;
    float ss = y0*y0 + y1*y1;
    #pragma unroll
    for (int o=32;o;o>>=1) ss += __shfl_xor(ss, o);
    float rs = rsqrtf(ss*(1.0f/128.0f) + EPS);
    *(unsigned*)(Qb + (((size_t)(b*16 + hh)*2048 + s)*128) + d0)
      = pack2(y0*rs*qn[d0]*SC2L, y1*rs*qn[d1]*SC2L);
  }
}

// ---------------- cross KV postprocess: K rmsnorm (no rope); V transposed copy ----------------
__global__ void k_crosskv_pp(const unsigned short* __restrict__ kvc, const float* __restrict__ kn,
                             unsigned short* __restrict__ Kb, unsigned short* __restrict__ Vt){
  const int row = blockIdx.x;           // b*2048 + sctx
  const int b = row>>11, s = row&2047;
  const int w = threadIdx.x>>6, l = threadIdx.x&63;
  const int d0 = 2*l, d1 = d0+1;
  #pragma unroll
  for (int it=0; it<2; ++it){
    const int hh = it*4 + w;
    const unsigned short* src = kvc + (size_t)row*1024 + hh*128;
    if (hh < 4){
      float x0 = bf2f(src[d0]), x1 = bf2f(src[d1]);
      float ss = x0*x0 + x1*x1;
      #pragma unroll
      for (int o=32;o;o>>=1) ss += __shfl_xor(ss, o);
      float rs = rsqrtf(ss*(1.0f/128.0f) + EPS);
      *(unsigned*)(Kb + (((size_t)(b*4 + hh)*2048 + s)*128) + d0)
        = pack2(x0*rs*kn[d0], x1*rs*kn[d1]);
    } else {
      const int hv = hh-4;
      size_t base = ((size_t)(b*4 + hv))*128*2048;
      Vt[base + (size_t)d0*2048 + s] = src[d0];
      Vt[base + (size_t)d1*2048 + s] = src[d1];
    }
  }
}

// ---------------- flash attention, GQA head-fused (round 9, verified best) ----------------
// 1024 threads = 16 waves; wave w -> head hq=w>>2, q-rows (w&3)*16+q of tile qt.
// K/V staged once per group tile, counted-vmcnt dbuf (vmcnt(2)). Log2-domain softmax,
// mask-bias LDS table, defer-max THR=8, cvt_pk packing.
// LDS: K0[0,16K) K1[16K,32K) V0[32K,48K) V1[48K,64K) P[64K,96K) bias[96K,104K)
template<bool QMASK>
__global__ __launch_bounds__(1024,1)
void k_attn(const unsigned short* __restrict__ Qg, const unsigned short* __restrict__ Kg,
            const unsigned short* __restrict__ Vtg,
            const unsigned char* __restrict__ qm, const unsigned char* __restrict__ km,
            unsigned short* __restrict__ Og, int H, int HKV){
  constexpr int SK = 2048, SQ = 2048, NT = SK/64;
  __shared__ __align__(16) char smem[106496];
  const int qt = blockIdx.x, hk = blockIdx.y, b = blockIdx.z;
  const int REP = H/HKV;
  const int tid = threadIdx.x, w = tid>>6, l = tid&63, g = l>>4, q = l&15;
  const int hq = w>>2, wsub = w&3;

  if (tid < 256){ // build f32 mask-bias table (0 visible, -3e38 masked)
    const unsigned long long mv = ((const unsigned long long*)(km + (size_t)b*SK))[tid];
    float* bl = (float*)(smem + 98304);
    #pragma unroll
    for (int j=0;j<8;++j)
      bl[tid*8+j] = ((mv>>(8*j)) & 0xffull) ? 0.0f : -3.0e38f;
  }

  const int h = hk*REP + hq;
  const size_t qrow = (size_t)(b*H + h)*SQ + qt*64 + wsub*16 + q;
  bf16x8 qf[4];
  #pragma unroll
  for (int ks=0;ks<4;++ks) qf[ks] = *(const bf16x8*)(Qg + qrow*128 + ks*32 + g*8);

  f32x4 oacc[8];
  #pragma unroll
  for (int i=0;i<8;++i) oacc[i] = f32x4{0.f,0.f,0.f,0.f};
  float m_run = -1.0e30f, l_run = 0.f;

  const unsigned short* Kt0 = Kg + (size_t)(b*HKV + hk)*SK*128;
  const unsigned short* Vt0 = Vtg + (size_t)(b*HKV + hk)*128*SK;
  const float* biasf = (const float*)(smem + 98304);
  char* Pl = smem + 65536 + w*2048;

  auto STAGE_T = [&](int t, int p){
    { // K: thread tid covers row r=tid>>4, chunk c16=tid&15
      int r = tid>>4, c16 = tid&15;
      int c = (c16 & 8) | ((c16 & 7) ^ (r & 7));
      int lofs = __builtin_amdgcn_readfirstlane(p*16384 + w*1024);
      gload16(Kt0 + (size_t)(t*64 + r)*128 + c*8, smem + lofs);
    }
    { // Vt: thread tid covers d=tid>>3, chunk c8=tid&7
      int d = tid>>3, c8 = tid&7;
      int c = c8 ^ (d & 7);
      int lofs = __builtin_amdgcn_readfirstlane(32768 + p*16384 + w*1024);
      gload16(Vt0 + (size_t)d*SK + t*64 + c*8, smem + lofs);
    }
  };

  STAGE_T(0, 0);

  for (int t=0; t<NT; ++t){
    const int p = t&1;
    asm volatile("s_waitcnt lgkmcnt(0)" ::: "memory");
    __builtin_amdgcn_s_barrier();
    asm volatile("" ::: "memory");
    if (t+1 < NT){
      STAGE_T(t+1, p^1);
      asm volatile("s_waitcnt vmcnt(2)" ::: "memory");  // tile t landed; t+1's 2 loads in flight
    } else {
      asm volatile("s_waitcnt vmcnt(0)" ::: "memory");
    }
    __builtin_amdgcn_s_barrier();
    asm volatile("" ::: "memory");

    const char* Kb_ = smem + p*16384;
    const char* Vb_ = smem + 32768 + p*16384;

    // S^T = K . Q (log2 domain)
    f32x4 sacc[4];
    #pragma unroll
    for (int i=0;i<4;++i) sacc[i] = f32x4{0.f,0.f,0.f,0.f};
    __builtin_amdgcn_s_setprio(1);
    #pragma unroll
    for (int ks=0;ks<4;++ks){
      #pragma unroll
      for (int mi=0;mi<4;++mi){
        int kcol = mi*16 + q;
        int c = 4*ks + g;
        int c16 = (c & 8) | ((c & 7) ^ (kcol & 7));
        bf16x8 ak = *(const bf16x8*)(Kb_ + kcol*256 + c16*16);
        sacc[mi] = __builtin_amdgcn_mfma_f32_16x16x32_bf16(ak, qf[ks], sacc[mi], 0,0,0);
      }
    }
    __builtin_amdgcn_s_setprio(0);

    // online softmax (log2) + mask bias + defer-max
    float sv[4][4];
    float mloc = -3.0e38f;
    #pragma unroll
    for (int mi=0;mi<4;++mi){
      f32x4 bb = *(const f32x4*)(biasf + t*64 + mi*16 + g*4);
      #pragma unroll
      for (int r=0;r<4;++r){
        float v = sacc[mi][r] + bb[r];
        sv[mi][r] = v;
        mloc = fmaxf(mloc, v);
      }
    }
    mloc = fmaxf(mloc, __shfl_xor(mloc, 16));
    mloc = fmaxf(mloc, __shfl_xor(mloc, 32));
    if (!__all(mloc - m_run <= 8.0f)){
      float mnew = fmaxf(m_run, mloc);
      float alpha = exp2a(m_run - mnew);
      l_run *= alpha;
      #pragma unroll
      for (int i=0;i<8;++i) oacc[i] *= alpha;
      m_run = mnew;
    }
    float rsum = 0.f;
    unsigned pb[4][2];
    #pragma unroll
    for (int mi=0;mi<4;++mi){
      float p0 = exp2a(sv[mi][0] - m_run);
      float p1 = exp2a(sv[mi][1] - m_run);
      float p2 = exp2a(sv[mi][2] - m_run);
      float p3 = exp2a(sv[mi][3] - m_run);
      rsum += (p0+p1)+(p2+p3);
      pb[mi][0] = cvtpk(p0, p1);
      pb[mi][1] = cvtpk(p2, p3);
    }
    rsum += __shfl_xor(rsum, 16);
    rsum += __shfl_xor(rsum, 32);
    l_run += rsum;

    // P -> wave-private LDS (XOR chunk swizzle)
    #pragma unroll
    for (int mi=0;mi<4;++mi){
      int c16 = (2*mi + (g>>1)) ^ (q & 7);
      uint2 uu; uu.x = pb[mi][0]; uu.y = pb[mi][1];
      *(uint2*)(Pl + q*128 + c16*16 + (g&1)*8) = uu;
    }
    asm volatile("" ::: "memory");

    // O^T += Vt . P^T
    __builtin_amdgcn_s_setprio(1);
    #pragma unroll
    for (int ks=0;ks<2;++ks){
      int c16 = (4*ks + g) ^ (q & 7);
      bf16x8 pf = *(const bf16x8*)(Pl + q*128 + c16*16);
      #pragma unroll
      for (int mi=0;mi<8;++mi){
        int d = mi*16 + q;
        bf16x8 vf = *(const bf16x8*)(Vb_ + d*128 + c16*16);
        oacc[mi] = __builtin_amdgcn_mfma_f32_16x16x32_bf16(vf, pf, oacc[mi], 0,0,0);
      }
    }
    __builtin_amdgcn_s_setprio(0);
  }

  float inv = (l_run > 0.f) ? 1.0f/l_run : 0.f;
  if (QMASK){
    if (!qm[(size_t)b*SQ + qt*64 + wsub*16 + q]) inv = 0.f;
  }
  // per-head transpose + store, 4 sequential phases (all 16 waves store each phase)
  float* Ot = (float*)smem;               // [128][65] f32 = 33,280 B
  const int qloc = tid>>4, seg = tid&15;
  #pragma unroll
  for (int ph=0; ph<4; ++ph){
    __syncthreads();
    if (hq == ph){
      #pragma unroll
      for (int mi=0;mi<8;++mi)
        #pragma unroll
        for (int r=0;r<4;++r){
          int d = mi*16 + g*4 + r;
          Ot[d*65 + wsub*16 + q] = oacc[mi][r]*inv;
        }
    }
    __syncthreads();
    int srow = qt*64 + qloc;
    size_t obase = ((size_t)b*SQ + srow)*(size_t)(H*128) + (size_t)(hk*REP + ph)*128 + seg*8;
    float vv[8];
    #pragma unroll
    for (int j=0;j<8;++j) vv[j] = Ot[(seg*8 + j)*65 + qloc];
    uint4 u;
    u.x = pack2(vv[0],vv[1]); u.y = pack2(vv[2],vv[3]);
    u.z = pack2(vv[4],vv[5]); u.w = pack2(vv[6],vv[7]);
    *(uint4*)(Og + obase) = u;
  }
}

// ---------------- launch ----------------
extern "C" void kernel_launch(void* const* d_in, const int* in_sizes, int n_in,
                              void* d_out, int out_size, void* d_ws, size_t ws_size,
                              hipStream_t stream){
  const float* x        = (const float*)d_in[0];
  const float* ctx      = (const float*)d_in[1];
  const float* fc       = (const float*)d_in[2];
  const float* fs       = (const float*)d_in[3];
  const float* wqkv     = (const float*)d_in[4];
  const float* wo_self  = (const float*)d_in[5];
  const float* qn_self  = (const float*)d_in[6];
  const float* kn_self  = (const float*)d_in[7];
  const float* wq       = (const float*)d_in[8];
  const float* wkv      = (const float*)d_in[9];
  const float* wo_cross = (const float*)d_in[10];
  const float* qn_cross = (const float*)d_in[11];
  const float* kn_cross = (const float*)d_in[12];
  const float* w1       = (const float*)d_in[13];
  const float* w2       = (const float*)d_in[14];
  const float* attn_nw  = (const float*)d_in[15];
  const float* cross_nw = (const float*)d_in[16];
  const float* ffn_nw   = (const float*)d_in[17];
  const unsigned* vis_raw   = (const unsigned*)d_in[18];
  const unsigned* cmask_raw = (const unsigned*)d_in[19];
  float* out = (float*)d_out;

  // HID padded 5464 -> 5632 (divisible by 256) for the new GEMM; zero-pad keeps exactness.
  char* ws = (char*)d_ws;
  unsigned short* wslot = (unsigned short*)(ws);               // 23,068,672 B (5632x2048 bf16)
  unsigned short* ctxbf = (unsigned short*)(ws +  23068672);   // 16,777,216
  unsigned short* nbuf  = (unsigned short*)(ws +  39845888);   // 16,777,216
  unsigned short* qkvb  = (unsigned short*)(ws +  56623104);   // 25,165,824
  unsigned short* Qb    = (unsigned short*)(ws +  81788928);   // 16,777,216
  unsigned short* Kb    = (unsigned short*)(ws +  98566144);   //  4,194,304
  unsigned short* Vtb   = (unsigned short*)(ws + 102760448);   //  4,194,304
  unsigned short* aob   = (unsigned short*)(ws + 106954752);   // aliased with midb (aob dead before w1)
  unsigned short* midb  = (unsigned short*)(ws + 106954752);   // 46,137,344 (4096x5632 bf16)
  unsigned char*  visN  = (unsigned char*)(ws + 153092096);    //  4,096
  unsigned char*  cmkN  = (unsigned char*)(ws + 153096192);    //  4,096 -> end 153,100,288
  unsigned short* qcb   = qkvb;                                // cross-q reuses qkv buffer
  unsigned short* kvcb  = qkvb + 8388608;                      // +16,777,216 B

  auto conv = [&](const float* s, unsigned short* dst, size_t n){
    int n4 = (int)(n>>2);
    k_conv<<<(n4+255)/256, 256, 0, stream>>>(s, dst, n4);
  };

  // ---- canonicalize masks (bool-as-bytes vs bool-as-int32) ----
  k_masknorm<<<1,256,0,stream>>>(vis_raw, cmask_raw, visN, cmkN);

  // ---- self attention path ----
  conv(ctx, ctxbf, (size_t)4096*2048);
  k_rms<<<4096,256,0,stream>>>(x, attn_nw, nbuf);
  conv(wqkv, wslot, (size_t)3072*2048);
  k_gemm2<0><<<dim3(12,32),512,0,stream>>>(nbuf, wslot, qkvb, nullptr, 4096,3072,2048);
  k_self_pp<<<4096,256,0,stream>>>(qkvb, fc, fs, qn_self, kn_self, Qb, Kb, Vtb);
  k_attn<true><<<dim3(32,4,2),1024,0,stream>>>(Qb, Kb, Vtb, visN, visN, aob, 16, 4);
  conv(wo_self, wslot, (size_t)2048*2048);
  k_gemm2<2><<<dim3(8,32),512,0,stream>>>(aob, wslot, out, x, 4096,2048,2048);

  // ---- cross attention path ----
  k_rms<<<4096,256,0,stream>>>(out, cross_nw, nbuf);
  conv(wq, wslot, (size_t)2048*2048);
  k_gemm2<0><<<dim3(8,32),512,0,stream>>>(nbuf, wslot, qcb, nullptr, 4096,2048,2048);
  conv(wkv, wslot, (size_t)1024*2048);
  k_gemm<0><<<dim3(8,32),256,0,stream>>>(ctxbf, wslot, kvcb, nullptr, 4096,1024,2048);
  k_crossq_pp<<<4096,256,0,stream>>>(qcb, fc, fs, qn_cross, Qb);
  k_crosskv_pp<<<4096,256,0,stream>>>(kvcb, kn_cross, Kb, Vtb);
  k_attn<false><<<dim3(32,4,2),1024,0,stream>>>(Qb, Kb, Vtb, nullptr, cmkN, aob, 16, 4);
  conv(wo_cross, wslot, (size_t)2048*2048);
  k_gemm2<2><<<dim3(8,32),512,0,stream>>>(aob, wslot, out, out, 4096,2048,2048);

  // ---- FFN (silu MLP), HID padded 5464 -> 5632 ----
  k_rms<<<4096,256,0,stream>>>(out, ffn_nw, nbuf);
  k_convpad_rows<<<(5632*2048/4+255)/256,256,0,stream>>>(w1, wslot, 5464, 2048, 5632);
  k_gemm2<1><<<dim3(22,32),512,0,stream>>>(nbuf, wslot, midb, nullptr, 4096,5632,2048);
  k_convpad_cols<<<(2048*5632/4+255)/256,256,0,stream>>>(w2, wslot, 2048, 5464, 5632);
  k_gemm2<2><<<dim3(8,32),512,0,stream>>>(midb, wslot, out, out, 4096,2048,5632);

  (void)in_sizes; (void)n_in; (void)out_size; (void)ws_size;
}